// Round 1
// baseline (3303.028 us; speedup 1.0000x reference)
//
#include <hip/hip_runtime.h>
#include <hip/hip_bf16.h>
#include <math.h>

#define BB   8
#define SS   256
#define DD   512
#define NHH  8
#define HDD  64
#define EE   4
#define LL   2
#define FFF  2048
#define RHH  256
#define VV   32000
#define MVV  2
#define TOK  (BB*SS)   // 2048

// ---------------- reduction helpers ----------------
__device__ __forceinline__ float wred_sum(float v){
#pragma unroll
  for(int o=32;o;o>>=1) v += __shfl_xor(v,o,64);
  return v;
}
__device__ __forceinline__ float wred_max(float v){
#pragma unroll
  for(int o=32;o;o>>=1) v = fmaxf(v, __shfl_xor(v,o,64));
  return v;
}
// 256-thread block sum. sh must be __shared__ float[4]. Safe for repeated use.
__device__ __forceinline__ float block_sum(float v, float* sh){
  v = wred_sum(v);
  if((threadIdx.x&63)==0) sh[threadIdx.x>>6]=v;
  __syncthreads();
  float t = sh[0]+sh[1]+sh[2]+sh[3];
  __syncthreads();
  return t;
}
__device__ __forceinline__ float gelu_exact(float x){
  return 0.5f*x*(1.f+erff(x*0.70710678118654752f));
}

// ---------------- embed + positional + input LN ----------------
__global__ void k_embed(const int* __restrict__ ids, const float* __restrict__ emb,
                        float* __restrict__ x){
  int tok = blockIdx.x;
  int s = tok & (SS-1);
  int tid = threadIdx.x;
  __shared__ float sh[4];
  int id = ids[tok];
  float v[2];
#pragma unroll
  for(int i=0;i<2;i++){
    int d = tid + i*256;
    float e = emb[(size_t)id*DD + d] * 22.627416997969522f; // sqrt(512)
    int j = d >> 1;
    float freq = expf((float)(2*j) * (-0.0179889460390160f)); // -ln(1e4)/512
    float arg = (float)s * freq;
    v[i] = e + ((d & 1) ? cosf(arg) : sinf(arg));
  }
  float m = block_sum(v[0]+v[1], sh) * (1.f/DD);
  float d0=v[0]-m, d1=v[1]-m;
  float var = block_sum(d0*d0+d1*d1, sh) * (1.f/DD);
  float inv = rsqrtf(var + 1e-5f);
  float* q = x + (size_t)tok*DD;
  q[tid] = d0*inv; q[tid+256] = d1*inv;
}

// ---------------- generic LN (optionally predicated on do[b]) ----------------
__global__ void k_ln(const float* __restrict__ in, float* __restrict__ out,
                     const int* __restrict__ dof){
  int tok = blockIdx.x;
  if(dof && !dof[tok>>8]) return;
  __shared__ float sh[4];
  int tid = threadIdx.x;
  const float* p = in + (size_t)tok*DD;
  float a0 = p[tid], a1 = p[tid+256];
  float m = block_sum(a0+a1, sh) * (1.f/DD);
  float d0=a0-m, d1=a1-m;
  float var = block_sum(d0*d0+d1*d1, sh) * (1.f/DD);
  float inv = rsqrtf(var + 1e-5f);
  float* q = out + (size_t)tok*DD;
  q[tid] = d0*inv; q[tid+256] = d1*inv;
}

// ---------------- summary = mean over S ----------------
__global__ void k_summary(const float* __restrict__ x, float* __restrict__ summary){
  int idx = blockIdx.x*256 + threadIdx.x; // 0..4095
  int b = idx >> 9, d = idx & 511;
  const float* p = x + (size_t)(b*SS)*DD + d;
  float s=0.f;
  for(int t=0;t<SS;t++) s += p[(size_t)t*DD];
  summary[idx] = s * (1.f/SS);
}

// ---------------- router: MLP -> LN -> mask -> argmax -> state update ----------------
__global__ void k_router(const float* __restrict__ summary,
                         const float* __restrict__ r_w1, const float* __restrict__ r_b1,
                         const float* __restrict__ r_w2, const float* __restrict__ r_b2,
                         const float* __restrict__ r_q,
                         int* __restrict__ action, int* __restrict__ dof,
                         int* __restrict__ visits, int* __restrict__ active, int step){
  int b = blockIdx.x; int tid = threadIdx.x;
  if(step==0 && tid==0){ active[b]=1; for(int e=0;e<EE;e++) visits[b*EE+e]=0; }
  __shared__ float hid[RHH];
  __shared__ float lg[EE+1];
  const float* srow = summary + (size_t)b*DD;
  const float* wrow = r_w1 + (size_t)tid*DD;
  float acc = r_b1[tid];
  for(int d=0; d<DD; d++) acc += srow[d]*wrow[d];
  hid[tid] = gelu_exact(acc);
  __syncthreads();
  if(tid<EE+1){
    const float* w2 = r_w2 + (size_t)tid*RHH;
    float a = r_b2[tid] + r_q[tid];
    for(int j=0;j<RHH;j++) a += hid[j]*w2[j];
    lg[tid]=a;
  }
  __syncthreads();
  if(tid==0){
    float m=0.f; for(int k=0;k<EE+1;k++) m+=lg[k]; m *= (1.f/(EE+1));
    float v=0.f; for(int k=0;k<EE+1;k++){float d=lg[k]-m; v+=d*d;} v *= (1.f/(EE+1));
    float inv = rsqrtf(v+1e-5f);
    float best=-1e38f; int bi=0;
    for(int k=0;k<EE+1;k++){
      float fl = (lg[k]-m)*inv;
      fl = fminf(fmaxf(fl,-10.f),10.f);
      if(k<EE && visits[b*EE+k]>=MVV) fl = -1e38f;
      if(fl > best){best=fl; bi=k;}
    }
    int dd = (active[b] && bi<EE) ? 1 : 0;
    action[b]=bi; dof[b]=dd;
    if(dd) visits[b*EE+bi]++;
    active[b]=dd;
  }
}

// ---------------- generic tiled fp32 GEMM: C = epi(A @ W^T + bias) ----------------
// A rows = tokens of batch b (64-row tile), W row-major [N,K].
// EPI: 0 = store, 1 = gelu+store, 2 = add-to-C (residual)
template<int EPI>
__global__ __launch_bounds__(256)
void k_gemm(const float* __restrict__ A1, const float* __restrict__ A2, int ksplit,
            const float* __restrict__ Wb, const float* __restrict__ bb,
            int wsel, int l, int N, int K,
            float* __restrict__ C,
            const int* __restrict__ action, const int* __restrict__ dof){
  int b = blockIdx.x;
  if(dof && !dof[b]) return;
  const float* W = Wb; const float* bias = bb;
  if(wsel){ size_t o=(size_t)(action[b]*LL+l); W += o*(size_t)N*K; bias += o*N; }
  int rowbase = b*SS + blockIdx.y*64;
  int colbase = blockIdx.z*64;
  __shared__ float As[16][68];
  __shared__ float Ws[16][68];
  int tid=threadIdx.x;
  int lr = tid>>2;          // 0..63
  int lk = (tid&3)*4;       // 0,4,8,12
  int tr = tid>>4, tc = tid&15;
  float acc[4][4]={};
  for(int k0=0;k0<K;k0+=16){
    int kk = k0+lk;
    float4 av;
    if(kk < ksplit) av = *(const float4*)(A1 + (size_t)(rowbase+lr)*ksplit + kk);
    else            av = *(const float4*)(A2 + (size_t)(rowbase+lr)*(K-ksplit) + (kk-ksplit));
    float4 wv = *(const float4*)(W + (size_t)(colbase+lr)*K + kk);
    As[lk+0][lr]=av.x; As[lk+1][lr]=av.y; As[lk+2][lr]=av.z; As[lk+3][lr]=av.w;
    Ws[lk+0][lr]=wv.x; Ws[lk+1][lr]=wv.y; Ws[lk+2][lr]=wv.z; Ws[lk+3][lr]=wv.w;
    __syncthreads();
#pragma unroll
    for(int k=0;k<16;k++){
      float4 a = *(const float4*)&As[k][tr*4];
      float4 w = *(const float4*)&Ws[k][tc*4];
      acc[0][0]+=a.x*w.x; acc[0][1]+=a.x*w.y; acc[0][2]+=a.x*w.z; acc[0][3]+=a.x*w.w;
      acc[1][0]+=a.y*w.x; acc[1][1]+=a.y*w.y; acc[1][2]+=a.y*w.z; acc[1][3]+=a.y*w.w;
      acc[2][0]+=a.z*w.x; acc[2][1]+=a.z*w.y; acc[2][2]+=a.z*w.z; acc[2][3]+=a.z*w.w;
      acc[3][0]+=a.w*w.x; acc[3][1]+=a.w*w.y; acc[3][2]+=a.w*w.z; acc[3][3]+=a.w*w.w;
    }
    __syncthreads();
  }
#pragma unroll
  for(int i=0;i<4;i++){
    int r = rowbase + tr*4 + i;
    float* crow = C + (size_t)r*N + colbase + tc*4;
#pragma unroll
    for(int j=0;j<4;j++){
      float v = acc[i][j] + bias[colbase + tc*4 + j];
      if(EPI==1) v = gelu_exact(v);
      if(EPI==2) crow[j] += v; else crow[j] = v;
    }
  }
}

// ---------------- attention: scores = Q K^T / 8 ----------------
__global__ __launch_bounds__(256)
void k_scores(const float* __restrict__ qkv, float* __restrict__ scores,
              const int* __restrict__ dof){
  int bh = blockIdx.x; int b = bh>>3, h = bh&7;
  if(!dof[b]) return;
  int qbase = blockIdx.y*64, kbase = blockIdx.z*64;
  __shared__ float Qs[16][68];
  __shared__ float Ks[16][68];
  int tid=threadIdx.x;
  int lr=tid>>2, lk=(tid&3)*4;
  int tr=tid>>4, tc=tid&15;
  float acc[4][4]={};
  const float* base = qkv + (size_t)b*SS*1536 + h*64;
  for(int k0=0;k0<HDD;k0+=16){
    int kk=k0+lk;
    float4 qv = *(const float4*)(base + (size_t)(qbase+lr)*1536 + kk);
    float4 kv = *(const float4*)(base + 512 + (size_t)(kbase+lr)*1536 + kk);
    Qs[lk+0][lr]=qv.x; Qs[lk+1][lr]=qv.y; Qs[lk+2][lr]=qv.z; Qs[lk+3][lr]=qv.w;
    Ks[lk+0][lr]=kv.x; Ks[lk+1][lr]=kv.y; Ks[lk+2][lr]=kv.z; Ks[lk+3][lr]=kv.w;
    __syncthreads();
#pragma unroll
    for(int k=0;k<16;k++){
      float4 a = *(const float4*)&Qs[k][tr*4];
      float4 w = *(const float4*)&Ks[k][tc*4];
      acc[0][0]+=a.x*w.x; acc[0][1]+=a.x*w.y; acc[0][2]+=a.x*w.z; acc[0][3]+=a.x*w.w;
      acc[1][0]+=a.y*w.x; acc[1][1]+=a.y*w.y; acc[1][2]+=a.y*w.z; acc[1][3]+=a.y*w.w;
      acc[2][0]+=a.z*w.x; acc[2][1]+=a.z*w.y; acc[2][2]+=a.z*w.z; acc[2][3]+=a.z*w.w;
      acc[3][0]+=a.w*w.x; acc[3][1]+=a.w*w.y; acc[3][2]+=a.w*w.z; acc[3][3]+=a.w*w.w;
    }
    __syncthreads();
  }
#pragma unroll
  for(int i=0;i<4;i++){
    float* srow = scores + ((size_t)bh*SS + qbase+tr*4+i)*SS + kbase + tc*4;
#pragma unroll
    for(int j=0;j<4;j++) srow[j] = acc[i][j]*0.125f;
  }
}

// ---------------- softmax over rows of scores ----------------
__global__ void k_softmax(float* __restrict__ scores, const int* __restrict__ dof){
  int row = blockIdx.x;            // (b*NH+h)*S + q
  if(!dof[row>>11]) return;
  __shared__ float sh[4];
  int tid = threadIdx.x;
  float* p = scores + (size_t)row*SS;
  float v = p[tid];
  float m = wred_max(v);
  if((tid&63)==0) sh[tid>>6]=m;
  __syncthreads();
  m = fmaxf(fmaxf(sh[0],sh[1]),fmaxf(sh[2],sh[3]));
  __syncthreads();
  float e = expf(v-m);
  float s = block_sum(e, sh);
  p[tid] = e/s;
}

// ---------------- attention: out = scores @ V ----------------
__global__ __launch_bounds__(256)
void k_attnv(const float* __restrict__ scores, const float* __restrict__ qkv,
             float* __restrict__ attno, const int* __restrict__ dof){
  int bh=blockIdx.x; int b=bh>>3, h=bh&7;
  if(!dof[b]) return;
  int qbase=blockIdx.y*64;
  __shared__ float Ss[16][68];
  __shared__ float Vs[16][68];
  int tid=threadIdx.x;
  int lr=tid>>2, lk=(tid&3)*4;
  int kr=tid>>4, dd4=(tid&15)*4;
  int tr=tid>>4, tc=tid&15;
  float acc[4][4]={};
  const float* vbase = qkv + (size_t)b*SS*1536 + 1024 + h*64;
  const float* srow = scores + (size_t)bh*SS*SS;
  for(int k0=0;k0<SS;k0+=16){
    float4 sv = *(const float4*)(srow + (size_t)(qbase+lr)*SS + k0+lk);
    Ss[lk+0][lr]=sv.x; Ss[lk+1][lr]=sv.y; Ss[lk+2][lr]=sv.z; Ss[lk+3][lr]=sv.w;
    *(float4*)&Vs[kr][dd4] = *(const float4*)(vbase + (size_t)(k0+kr)*1536 + dd4);
    __syncthreads();
#pragma unroll
    for(int k=0;k<16;k++){
      float4 a = *(const float4*)&Ss[k][tr*4];
      float4 w = *(const float4*)&Vs[k][tc*4];
      acc[0][0]+=a.x*w.x; acc[0][1]+=a.x*w.y; acc[0][2]+=a.x*w.z; acc[0][3]+=a.x*w.w;
      acc[1][0]+=a.y*w.x; acc[1][1]+=a.y*w.y; acc[1][2]+=a.y*w.z; acc[1][3]+=a.y*w.w;
      acc[2][0]+=a.z*w.x; acc[2][1]+=a.z*w.y; acc[2][2]+=a.z*w.z; acc[2][3]+=a.z*w.w;
      acc[3][0]+=a.w*w.x; acc[3][1]+=a.w*w.y; acc[3][2]+=a.w*w.z; acc[3][3]+=a.w*w.w;
    }
    __syncthreads();
  }
#pragma unroll
  for(int i=0;i<4;i++){
    float* orow = attno + (size_t)(b*SS + qbase+tr*4+i)*DD + h*64 + tc*4;
#pragma unroll
    for(int j=0;j<4;j++) orow[j] = acc[i][j];
  }
}

// ---------------- gated residual: x += LN(z + sigmoid(g)*ao) ----------------
__global__ void k_gateres(const float* __restrict__ z, const float* __restrict__ ao,
                          const float* __restrict__ g, float* __restrict__ x,
                          const int* __restrict__ dof){
  int tok = blockIdx.x; if(!dof[tok>>8]) return;
  __shared__ float sh[4];
  int tid=threadIdx.x;
  size_t base=(size_t)tok*DD;
  float zz0=z[base+tid],     aa0=ao[base+tid],     gg0=g[base+tid];
  float zz1=z[base+tid+256], aa1=ao[base+tid+256], gg1=g[base+tid+256];
  float t0 = zz0 + aa0/(1.f+expf(-gg0));
  float t1 = zz1 + aa1/(1.f+expf(-gg1));
  float m = block_sum(t0+t1,sh)*(1.f/DD);
  float d0=t0-m, d1=t1-m;
  float var=block_sum(d0*d0+d1*d1,sh)*(1.f/DD);
  float inv=rsqrtf(var+1e-5f);
  x[base+tid]     += d0*inv;
  x[base+tid+256] += d1*inv;
}

// ---------------- expert tag add ----------------
__global__ void k_tag(float* __restrict__ x, const float* __restrict__ tag,
                      const int* __restrict__ action, const int* __restrict__ dof){
  int tok=blockIdx.x; int b=tok>>8; if(!dof[b]) return;
  const float* t = tag + (size_t)action[b]*DD;
  size_t base=(size_t)tok*DD;
  x[base+threadIdx.x]     += t[threadIdx.x];
  x[base+threadIdx.x+256] += t[threadIdx.x+256];
}

// ---------------- host launcher ----------------
extern "C" void kernel_launch(void* const* d_in, const int* in_sizes, int n_in,
                              void* d_out, int out_size, void* d_ws, size_t ws_size,
                              hipStream_t stream){
  const int*   ids   = (const int*)d_in[0];
  const float* emb   = (const float*)d_in[1];
  const float* r_w1  = (const float*)d_in[2];
  const float* r_b1  = (const float*)d_in[3];
  const float* r_w2  = (const float*)d_in[4];
  const float* r_b2  = (const float*)d_in[5];
  const float* r_q   = (const float*)d_in[6];
  const float* in_w  = (const float*)d_in[7];
  const float* in_b  = (const float*)d_in[8];
  const float* out_w = (const float*)d_in[9];
  const float* out_b = (const float*)d_in[10];
  const float* gate_w= (const float*)d_in[11];
  const float* gate_b= (const float*)d_in[12];
  const float* f_w1  = (const float*)d_in[13];
  const float* f_b1  = (const float*)d_in[14];
  const float* f_w2  = (const float*)d_in[15];
  const float* f_b2  = (const float*)d_in[16];
  const float* tag   = (const float*)d_in[17];
  const float* lm_w  = (const float*)d_in[18];
  const float* lm_b  = (const float*)d_in[19];
  float* out = (float*)d_out;
  float* ws  = (float*)d_ws;

  const size_t M = (size_t)TOK*DD;   // 1,048,576 floats
  float* x      = ws;                 // [TOK,512]
  float* z      = ws + 1*M;           // LN1 out
  float* z2     = ws + 2*M;           // LN2 out
  float* attno  = ws + 3*M;           // attention pre-proj
  float* ao     = ws + 4*M;           // attention out-proj
  float* gtmp   = ws + 5*M;           // gate pre-sigmoid
  float* qkv    = ws + 6*M;           // [TOK,1536] (3M floats)
  float* scores = ws + 9*M;           // [B*NH,S,S] = 4M floats (aliased with ffh)
  float* ffh    = ws + 9*M;           // [TOK,FF]  = 4M floats (alias: disjoint lifetimes)
  float* summary= ws + 13*M;          // [B,512]
  int*   ipool  = (int*)(summary + BB*DD);
  int* action = ipool; int* dof = ipool+BB; int* active = ipool+2*BB; int* visits = ipool+3*BB;

  k_embed<<<TOK,256,0,stream>>>(ids, emb, x);

  for(int step=0; step<3; step++){
    k_summary<<<(BB*DD)/256,256,0,stream>>>(x, summary);
    k_router<<<BB,256,0,stream>>>(summary,r_w1,r_b1,r_w2,r_b2,r_q,action,dof,visits,active,step);
    for(int l=0; l<LL; l++){
      k_ln<<<TOK,256,0,stream>>>(x, z, dof);
      k_gemm<0><<<dim3(BB,4,24),256,0,stream>>>(z,nullptr,DD, in_w,in_b,1,l, 3*DD,DD, qkv, action,dof);
      k_scores<<<dim3(BB*NHH,4,4),256,0,stream>>>(qkv, scores, dof);
      k_softmax<<<BB*NHH*SS,256,0,stream>>>(scores, dof);
      k_attnv<<<dim3(BB*NHH,4),256,0,stream>>>(scores, qkv, attno, dof);
      k_gemm<0><<<dim3(BB,4,8),256,0,stream>>>(attno,nullptr,DD, out_w,out_b,1,l, DD,DD, ao, action,dof);
      k_gemm<0><<<dim3(BB,4,8),256,0,stream>>>(z,ao,DD, gate_w,gate_b,1,l, DD,2*DD, gtmp, action,dof);
      k_gateres<<<TOK,256,0,stream>>>(z,ao,gtmp,x,dof);
      k_ln<<<TOK,256,0,stream>>>(x, z2, dof);
      k_gemm<1><<<dim3(BB,4,32),256,0,stream>>>(z2,nullptr,DD, f_w1,f_b1,1,l, FFF,DD, ffh, action,dof);
      k_gemm<2><<<dim3(BB,4,8),256,0,stream>>>(ffh,nullptr,FFF, f_w2,f_b2,1,l, DD,FFF, x, action,dof);
    }
    k_tag<<<TOK,256,0,stream>>>(x,tag,action,dof);
  }

  k_ln<<<TOK,256,0,stream>>>(x, z, nullptr);
  k_gemm<0><<<dim3(BB,4,VV/64),256,0,stream>>>(z,nullptr,DD, lm_w,lm_b,0,0, VV,DD, out, nullptr,nullptr);
}

// Round 2
// 1489.245 us; speedup vs baseline: 2.2179x; 2.2179x over previous
//
#include <hip/hip_runtime.h>
#include <hip/hip_bf16.h>
#include <math.h>

#define BB   8
#define SS   256
#define DD   512
#define NHH  8
#define HDD  64
#define EE   4
#define LL   2
#define FFF  2048
#define RHH  256
#define VV   32000
#define MVV  2
#define TOK  (BB*SS)   // 2048

typedef __attribute__((ext_vector_type(8))) short bf16x8;
typedef __attribute__((ext_vector_type(4))) float f32x4;

// ---------------- helpers ----------------
__device__ __forceinline__ float wred_sum(float v){
#pragma unroll
  for(int o=32;o;o>>=1) v += __shfl_xor(v,o,64);
  return v;
}
__device__ __forceinline__ float wred_max(float v){
#pragma unroll
  for(int o=32;o;o>>=1) v = fmaxf(v, __shfl_xor(v,o,64));
  return v;
}
__device__ __forceinline__ float block_sum(float v, float* sh){
  v = wred_sum(v);
  if((threadIdx.x&63)==0) sh[threadIdx.x>>6]=v;
  __syncthreads();
  float t = sh[0]+sh[1]+sh[2]+sh[3];
  __syncthreads();
  return t;
}
__device__ __forceinline__ float gelu_exact(float x){
  return 0.5f*x*(1.f+erff(x*0.70710678118654752f));
}
__device__ __forceinline__ unsigned short bfr(float f){
  union{float f; unsigned u;} c; c.f=f;
  unsigned u = c.u;
  return (unsigned short)((u + 0x7FFFu + ((u>>16)&1u)) >> 16);
}

// ---------------- f32 -> bf16 cast (grid-stride over float4) ----------------
__global__ void k_cast(const float* __restrict__ in, unsigned short* __restrict__ out, int n4){
  int i = blockIdx.x*256 + threadIdx.x;
  if(i >= n4) return;
  float4 v = ((const float4*)in)[i];
  ushort4 o;
  o.x = bfr(v.x); o.y = bfr(v.y); o.z = bfr(v.z); o.w = bfr(v.w);
  ((ushort4*)out)[i] = o;
}

// ---------------- embed + positional + input LN ----------------
__global__ void k_embed(const int* __restrict__ ids, const float* __restrict__ emb,
                        float* __restrict__ x){
  int tok = blockIdx.x;
  int s = tok & (SS-1);
  int tid = threadIdx.x;
  __shared__ float sh[4];
  int id = ids[tok];
  float v[2];
#pragma unroll
  for(int i=0;i<2;i++){
    int d = tid + i*256;
    float e = emb[(size_t)id*DD + d] * 22.627416997969522f; // sqrt(512)
    int j = d >> 1;
    float freq = expf((float)(2*j) * (-0.0179889460390160f)); // -ln(1e4)/512
    float arg = (float)s * freq;
    v[i] = e + ((d & 1) ? cosf(arg) : sinf(arg));
  }
  float m = block_sum(v[0]+v[1], sh) * (1.f/DD);
  float d0=v[0]-m, d1=v[1]-m;
  float var = block_sum(d0*d0+d1*d1, sh) * (1.f/DD);
  float inv = rsqrtf(var + 1e-5f);
  float* q = x + (size_t)tok*DD;
  q[tid] = d0*inv; q[tid+256] = d1*inv;
}

// ---------------- LN: optional f32 out, optional bf16 out, predicated ----------------
__global__ void k_ln(const float* __restrict__ in, float* __restrict__ outf,
                     unsigned short* __restrict__ outb, const int* __restrict__ dof){
  int tok = blockIdx.x;
  if(dof && !dof[tok>>8]) return;
  __shared__ float sh[4];
  int tid = threadIdx.x;
  const float* p = in + (size_t)tok*DD;
  float a0 = p[tid], a1 = p[tid+256];
  float m = block_sum(a0+a1, sh) * (1.f/DD);
  float d0=a0-m, d1=a1-m;
  float var = block_sum(d0*d0+d1*d1, sh) * (1.f/DD);
  float inv = rsqrtf(var + 1e-5f);
  float r0 = d0*inv, r1 = d1*inv;
  if(outf){ float* q = outf + (size_t)tok*DD; q[tid] = r0; q[tid+256] = r1; }
  if(outb){ unsigned short* q = outb + (size_t)tok*DD; q[tid] = bfr(r0); q[tid+256] = bfr(r1); }
}

// ---------------- summary = mean over S ----------------
__global__ void k_summary(const float* __restrict__ x, float* __restrict__ summary){
  int idx = blockIdx.x*256 + threadIdx.x; // 0..4095
  int b = idx >> 9, d = idx & 511;
  const float* p = x + (size_t)(b*SS)*DD + d;
  float s=0.f;
  for(int t=0;t<SS;t++) s += p[(size_t)t*DD];
  summary[idx] = s * (1.f/SS);
}

// ---------------- router ----------------
__global__ void k_router(const float* __restrict__ summary,
                         const float* __restrict__ r_w1, const float* __restrict__ r_b1,
                         const float* __restrict__ r_w2, const float* __restrict__ r_b2,
                         const float* __restrict__ r_q,
                         int* __restrict__ action, int* __restrict__ dof,
                         int* __restrict__ visits, int* __restrict__ active, int step){
  int b = blockIdx.x; int tid = threadIdx.x;
  if(step==0 && tid==0){ active[b]=1; for(int e=0;e<EE;e++) visits[b*EE+e]=0; }
  __shared__ float hid[RHH];
  __shared__ float lg[EE+1];
  const float* srow = summary + (size_t)b*DD;
  const float* wrow = r_w1 + (size_t)tid*DD;
  float acc = r_b1[tid];
  for(int d=0; d<DD; d++) acc += srow[d]*wrow[d];
  hid[tid] = gelu_exact(acc);
  __syncthreads();
  if(tid<EE+1){
    const float* w2 = r_w2 + (size_t)tid*RHH;
    float a = r_b2[tid] + r_q[tid];
    for(int j=0;j<RHH;j++) a += hid[j]*w2[j];
    lg[tid]=a;
  }
  __syncthreads();
  if(tid==0){
    float m=0.f; for(int k=0;k<EE+1;k++) m+=lg[k]; m *= (1.f/(EE+1));
    float v=0.f; for(int k=0;k<EE+1;k++){float d=lg[k]-m; v+=d*d;} v *= (1.f/(EE+1));
    float inv = rsqrtf(v+1e-5f);
    float best=-1e38f; int bi=0;
    for(int k=0;k<EE+1;k++){
      float fl = (lg[k]-m)*inv;
      fl = fminf(fmaxf(fl,-10.f),10.f);
      if(k<EE && visits[b*EE+k]>=MVV) fl = -1e38f;
      if(fl > best){best=fl; bi=k;}
    }
    int dd = (active[b] && bi<EE) ? 1 : 0;
    action[b]=bi; dof[b]=dd;
    if(dd) visits[b*EE+bi]++;
    active[b]=dd;
  }
}

// ---------------- bf16 MFMA GEMM: C = epi(A @ W^T + bias) ----------------
// 128x128 tile, BK=32, 4 waves each computing 64x64 (4x4 frags of 16x16x32).
// A rows are tokens; W row-major [N,K] bf16. A may be split (concat) at ksplit.
// XOR swizzle (cb ^ (row&3)<<4) applied on pre-swizzled global source AND LDS read.
// EPI: 0 = f32 store (+opt bf16 store), 1 = gelu -> bf16 store only, 2 = f32 +=
template<int EPI>
__global__ __launch_bounds__(256)
void k_mgemm(const unsigned short* __restrict__ A1, const unsigned short* __restrict__ A2,
             int ksplit,
             const unsigned short* __restrict__ Wb, const float* __restrict__ bb,
             int wsel, int l, int N, int K,
             float* __restrict__ Cf, unsigned short* __restrict__ Cb,
             const int* __restrict__ action, const int* __restrict__ dof){
  int b = blockIdx.x;
  if(dof && !dof[b]) return;
  const unsigned short* W = Wb; const float* bias = bb;
  if(wsel){ size_t o = (size_t)(action[b]*LL + l); W += o*(size_t)N*K; bias += o*N; }
  int rowbase = b*SS + blockIdx.y*128;
  int colbase = blockIdx.z*128;
  __shared__ unsigned short sA[128*32];
  __shared__ unsigned short sW[128*32];
  int t = threadIdx.x;
  int lane = t & 63;
  int w = t >> 6, wr = w >> 1, wc = w & 1;

  // staging geometry: issue i covers tile rows i*64 + t/4, 16B chunk (t&3)
  int sr0  = t >> 2;
  int scb0 = (t & 3) << 4;

  f32x4 acc[4][4];
#pragma unroll
  for(int m=0;m<4;m++)
#pragma unroll
    for(int n=0;n<4;n++) acc[m][n] = (f32x4){0.f,0.f,0.f,0.f};

  int frow = lane & 15;
  int fkb  = (lane >> 4) << 4;   // byte 0,16,32,48

  for(int k0 = 0; k0 < K; k0 += 32){
    const unsigned short* Ab; int kb0, kstride;
    if(k0 < ksplit){ Ab = A1; kb0 = k0;          kstride = ksplit; }
    else           { Ab = A2; kb0 = k0 - ksplit; kstride = K - ksplit; }
#pragma unroll
    for(int i = 0; i < 2; i++){
      int r  = i*64 + sr0;
      int cb = scb0 ^ ((r & 3) << 4);
      const unsigned short* gp = Ab + (size_t)(rowbase + r)*kstride + kb0 + (cb >> 1);
      __builtin_amdgcn_global_load_lds((const __attribute__((address_space(1))) void*)gp,
          (__attribute__((address_space(3))) void*)(sA + (size_t)i*2048 + (size_t)t*8), 16, 0, 0);
      const unsigned short* gw = W + (size_t)(colbase + r)*K + k0 + (cb >> 1);
      __builtin_amdgcn_global_load_lds((const __attribute__((address_space(1))) void*)gw,
          (__attribute__((address_space(3))) void*)(sW + (size_t)i*2048 + (size_t)t*8), 16, 0, 0);
    }
    __syncthreads();
    bf16x8 af[4], wf[4];
#pragma unroll
    for(int m = 0; m < 4; m++){
      int r  = wr*64 + m*16 + frow;
      int cb = fkb ^ ((r & 3) << 4);
      af[m] = *(const bf16x8*)(sA + r*32 + (cb >> 1));
    }
#pragma unroll
    for(int n = 0; n < 4; n++){
      int r  = wc*64 + n*16 + frow;
      int cb = fkb ^ ((r & 3) << 4);
      wf[n] = *(const bf16x8*)(sW + r*32 + (cb >> 1));
    }
#pragma unroll
    for(int m = 0; m < 4; m++)
#pragma unroll
      for(int n = 0; n < 4; n++)
        acc[m][n] = __builtin_amdgcn_mfma_f32_16x16x32_bf16(af[m], wf[n], acc[m][n], 0, 0, 0);
    __syncthreads();
  }
  // epilogue: D row=(lane>>4)*4+j, col=lane&15 within each 16x16 frag
  int orow0 = rowbase + wr*64 + ((lane >> 4) << 2);
  int ocol0 = colbase + wc*64 + (lane & 15);
#pragma unroll
  for(int m = 0; m < 4; m++){
#pragma unroll
    for(int n = 0; n < 4; n++){
      int col = ocol0 + n*16;
      float bv = bias[col];
#pragma unroll
      for(int j = 0; j < 4; j++){
        int row = orow0 + m*16 + j;
        size_t idx = (size_t)row*N + col;
        float v = acc[m][n][j] + bv;
        if(EPI == 0){ Cf[idx] = v; if(Cb) Cb[idx] = bfr(v); }
        else if(EPI == 1){ Cb[idx] = bfr(gelu_exact(v)); }
        else { Cf[idx] += v; }
      }
    }
  }
}

// ---------------- attention: scores = Q K^T / 8 (fp32) ----------------
__global__ __launch_bounds__(256)
void k_scores(const float* __restrict__ qkv, float* __restrict__ scores,
              const int* __restrict__ dof){
  int bh = blockIdx.x; int b = bh>>3, h = bh&7;
  if(!dof[b]) return;
  int qbase = blockIdx.y*64, kbase = blockIdx.z*64;
  __shared__ float Qs[16][68];
  __shared__ float Ks[16][68];
  int tid=threadIdx.x;
  int lr=tid>>2, lk=(tid&3)*4;
  int tr=tid>>4, tc=tid&15;
  float acc[4][4]={};
  const float* base = qkv + (size_t)b*SS*1536 + h*64;
  for(int k0=0;k0<HDD;k0+=16){
    int kk=k0+lk;
    float4 qv = *(const float4*)(base + (size_t)(qbase+lr)*1536 + kk);
    float4 kv = *(const float4*)(base + 512 + (size_t)(kbase+lr)*1536 + kk);
    Qs[lk+0][lr]=qv.x; Qs[lk+1][lr]=qv.y; Qs[lk+2][lr]=qv.z; Qs[lk+3][lr]=qv.w;
    Ks[lk+0][lr]=kv.x; Ks[lk+1][lr]=kv.y; Ks[lk+2][lr]=kv.z; Ks[lk+3][lr]=kv.w;
    __syncthreads();
#pragma unroll
    for(int k=0;k<16;k++){
      float4 a = *(const float4*)&Qs[k][tr*4];
      float4 w = *(const float4*)&Ks[k][tc*4];
      acc[0][0]+=a.x*w.x; acc[0][1]+=a.x*w.y; acc[0][2]+=a.x*w.z; acc[0][3]+=a.x*w.w;
      acc[1][0]+=a.y*w.x; acc[1][1]+=a.y*w.y; acc[1][2]+=a.y*w.z; acc[1][3]+=a.y*w.w;
      acc[2][0]+=a.z*w.x; acc[2][1]+=a.z*w.y; acc[2][2]+=a.z*w.z; acc[2][3]+=a.z*w.w;
      acc[3][0]+=a.w*w.x; acc[3][1]+=a.w*w.y; acc[3][2]+=a.w*w.z; acc[3][3]+=a.w*w.w;
    }
    __syncthreads();
  }
#pragma unroll
  for(int i=0;i<4;i++){
    float* srow = scores + ((size_t)bh*SS + qbase+tr*4+i)*SS + kbase + tc*4;
#pragma unroll
    for(int j=0;j<4;j++) srow[j] = acc[i][j]*0.125f;
  }
}

// ---------------- softmax ----------------
__global__ void k_softmax(float* __restrict__ scores, const int* __restrict__ dof){
  int row = blockIdx.x;
  if(!dof[row>>11]) return;
  __shared__ float sh[4];
  int tid = threadIdx.x;
  float* p = scores + (size_t)row*SS;
  float v = p[tid];
  float m = wred_max(v);
  if((tid&63)==0) sh[tid>>6]=m;
  __syncthreads();
  m = fmaxf(fmaxf(sh[0],sh[1]),fmaxf(sh[2],sh[3]));
  __syncthreads();
  float e = expf(v-m);
  float s = block_sum(e, sh);
  p[tid] = e/s;
}

// ---------------- attn out = scores @ V (fp32 in, bf16 out) ----------------
__global__ __launch_bounds__(256)
void k_attnv(const float* __restrict__ scores, const float* __restrict__ qkv,
             unsigned short* __restrict__ attno_bf, const int* __restrict__ dof){
  int bh=blockIdx.x; int b=bh>>3, h=bh&7;
  if(!dof[b]) return;
  int qbase=blockIdx.y*64;
  __shared__ float Ss[16][68];
  __shared__ float Vs[16][68];
  int tid=threadIdx.x;
  int lr=tid>>2, lk=(tid&3)*4;
  int kr=tid>>4, dd4=(tid&15)*4;
  int tr=tid>>4, tc=tid&15;
  float acc[4][4]={};
  const float* vbase = qkv + (size_t)b*SS*1536 + 1024 + h*64;
  const float* srow = scores + (size_t)bh*SS*SS;
  for(int k0=0;k0<SS;k0+=16){
    float4 sv = *(const float4*)(srow + (size_t)(qbase+lr)*SS + k0+lk);
    Ss[lk+0][lr]=sv.x; Ss[lk+1][lr]=sv.y; Ss[lk+2][lr]=sv.z; Ss[lk+3][lr]=sv.w;
    *(float4*)&Vs[kr][dd4] = *(const float4*)(vbase + (size_t)(k0+kr)*1536 + dd4);
    __syncthreads();
#pragma unroll
    for(int k=0;k<16;k++){
      float4 a = *(const float4*)&Ss[k][tr*4];
      float4 w = *(const float4*)&Vs[k][tc*4];
      acc[0][0]+=a.x*w.x; acc[0][1]+=a.x*w.y; acc[0][2]+=a.x*w.z; acc[0][3]+=a.x*w.w;
      acc[1][0]+=a.y*w.x; acc[1][1]+=a.y*w.y; acc[1][2]+=a.y*w.z; acc[1][3]+=a.y*w.w;
      acc[2][0]+=a.z*w.x; acc[2][1]+=a.z*w.y; acc[2][2]+=a.z*w.z; acc[2][3]+=a.z*w.w;
      acc[3][0]+=a.w*w.x; acc[3][1]+=a.w*w.y; acc[3][2]+=a.w*w.z; acc[3][3]+=a.w*w.w;
    }
    __syncthreads();
  }
#pragma unroll
  for(int i=0;i<4;i++){
    unsigned short* orow = attno_bf + (size_t)(b*SS + qbase+tr*4+i)*DD + h*64 + tc*4;
#pragma unroll
    for(int j=0;j<4;j++) orow[j] = bfr(acc[i][j]);
  }
}

// ---------------- gated residual: x += LN(z + sigmoid(g)*ao) ----------------
__global__ void k_gateres(const float* __restrict__ z, const float* __restrict__ ao,
                          const float* __restrict__ g, float* __restrict__ x,
                          const int* __restrict__ dof){
  int tok = blockIdx.x; if(!dof[tok>>8]) return;
  __shared__ float sh[4];
  int tid=threadIdx.x;
  size_t base=(size_t)tok*DD;
  float zz0=z[base+tid],     aa0=ao[base+tid],     gg0=g[base+tid];
  float zz1=z[base+tid+256], aa1=ao[base+tid+256], gg1=g[base+tid+256];
  float t0 = zz0 + aa0/(1.f+expf(-gg0));
  float t1 = zz1 + aa1/(1.f+expf(-gg1));
  float m = block_sum(t0+t1,sh)*(1.f/DD);
  float d0=t0-m, d1=t1-m;
  float var=block_sum(d0*d0+d1*d1,sh)*(1.f/DD);
  float inv=rsqrtf(var+1e-5f);
  x[base+tid]     += d0*inv;
  x[base+tid+256] += d1*inv;
}

// ---------------- expert tag add ----------------
__global__ void k_tag(float* __restrict__ x, const float* __restrict__ tag,
                      const int* __restrict__ action, const int* __restrict__ dof){
  int tok=blockIdx.x; int b=tok>>8; if(!dof[b]) return;
  const float* t = tag + (size_t)action[b]*DD;
  size_t base=(size_t)tok*DD;
  x[base+threadIdx.x]     += t[threadIdx.x];
  x[base+threadIdx.x+256] += t[threadIdx.x+256];
}

// ---------------- host launcher ----------------
extern "C" void kernel_launch(void* const* d_in, const int* in_sizes, int n_in,
                              void* d_out, int out_size, void* d_ws, size_t ws_size,
                              hipStream_t stream){
  const int*   ids   = (const int*)d_in[0];
  const float* emb   = (const float*)d_in[1];
  const float* r_w1  = (const float*)d_in[2];
  const float* r_b1  = (const float*)d_in[3];
  const float* r_w2  = (const float*)d_in[4];
  const float* r_b2  = (const float*)d_in[5];
  const float* r_q   = (const float*)d_in[6];
  const float* in_w  = (const float*)d_in[7];
  const float* in_b  = (const float*)d_in[8];
  const float* out_w = (const float*)d_in[9];
  const float* out_b = (const float*)d_in[10];
  const float* gate_w= (const float*)d_in[11];
  const float* gate_b= (const float*)d_in[12];
  const float* f_w1  = (const float*)d_in[13];
  const float* f_b1  = (const float*)d_in[14];
  const float* f_w2  = (const float*)d_in[15];
  const float* f_b2  = (const float*)d_in[16];
  const float* tag   = (const float*)d_in[17];
  const float* lm_w  = (const float*)d_in[18];
  const float* lm_b  = (const float*)d_in[19];
  float* out = (float*)d_out;
  float* ws  = (float*)d_ws;

  const size_t M = (size_t)TOK*DD;   // 1,048,576
  float* x      = ws;            // 1M f32
  float* z      = ws + 1*M;      // 1M f32
  float* ao     = ws + 2*M;      // 1M f32
  float* gtmp   = ws + 3*M;      // 1M f32
  float* qkv    = ws + 4*M;      // 3M f32
  float* scores = ws + 7*M;      // 4M f32
  float* summary= ws + 11*M;     // 4096 f32
  int*   ipool  = (int*)(summary + 4096);
  int* action = ipool; int* dof = ipool+BB; int* active = ipool+2*BB; int* visits = ipool+3*BB;

  unsigned short* ub = (unsigned short*)(ws + 11*M + 8192);
  unsigned short* z_bf     = ub;          // 1M
  unsigned short* ao_bf    = ub + 1*M;    // 1M
  unsigned short* z2_bf    = ub + 2*M;    // 1M
  unsigned short* attno_bf = ub + 3*M;    // 1M
  unsigned short* ffh_bf   = (unsigned short*)scores; // alias: 4M bf16 in 4M f32 region (disjoint lifetime)
  unsigned short* wb = ub + 4*M;
  unsigned short* in_wb   = wb;                       // 6,291,456
  unsigned short* out_wb  = in_wb  + (size_t)EE*LL*3*DD*DD;
  unsigned short* gate_wb = out_wb + (size_t)EE*LL*DD*DD;
  unsigned short* f_w1b   = gate_wb+ (size_t)EE*LL*DD*2*DD;
  unsigned short* f_w2b   = f_w1b  + (size_t)EE*LL*FFF*DD;
  unsigned short* lm_wb   = f_w2b  + (size_t)EE*LL*DD*FFF;

  // weight casts (every launch; ~55us of pure BW)
  k_cast<<<6144, 256,0,stream>>>(in_w,   in_wb,   (int)((size_t)EE*LL*3*DD*DD/4));
  k_cast<<<2048, 256,0,stream>>>(out_w,  out_wb,  (int)((size_t)EE*LL*DD*DD/4));
  k_cast<<<4096, 256,0,stream>>>(gate_w, gate_wb, (int)((size_t)EE*LL*DD*2*DD/4));
  k_cast<<<8192, 256,0,stream>>>(f_w1,   f_w1b,   (int)((size_t)EE*LL*FFF*DD/4));
  k_cast<<<8192, 256,0,stream>>>(f_w2,   f_w2b,   (int)((size_t)EE*LL*DD*FFF/4));
  k_cast<<<16000,256,0,stream>>>(lm_w,   lm_wb,   (int)((size_t)VV*DD/4));

  k_embed<<<TOK,256,0,stream>>>(ids, emb, x);

  for(int step=0; step<3; step++){
    k_summary<<<(BB*DD)/256,256,0,stream>>>(x, summary);
    k_router<<<BB,256,0,stream>>>(summary,r_w1,r_b1,r_w2,r_b2,r_q,action,dof,visits,active,step);
    for(int l=0; l<LL; l++){
      k_ln<<<TOK,256,0,stream>>>(x, z, z_bf, dof);
      k_mgemm<0><<<dim3(BB,2,12),256,0,stream>>>(z_bf,nullptr,DD, in_wb,in_b,1,l, 3*DD,DD, qkv,nullptr, action,dof);
      k_scores<<<dim3(BB*NHH,4,4),256,0,stream>>>(qkv, scores, dof);
      k_softmax<<<BB*NHH*SS,256,0,stream>>>(scores, dof);
      k_attnv<<<dim3(BB*NHH,4),256,0,stream>>>(scores, qkv, attno_bf, dof);
      k_mgemm<0><<<dim3(BB,2,4),256,0,stream>>>(attno_bf,nullptr,DD, out_wb,out_b,1,l, DD,DD, ao,ao_bf, action,dof);
      k_mgemm<0><<<dim3(BB,2,4),256,0,stream>>>(z_bf,ao_bf,DD, gate_wb,gate_b,1,l, DD,2*DD, gtmp,nullptr, action,dof);
      k_gateres<<<TOK,256,0,stream>>>(z,ao,gtmp,x,dof);
      k_ln<<<TOK,256,0,stream>>>(x, nullptr, z2_bf, dof);
      k_mgemm<1><<<dim3(BB,2,16),256,0,stream>>>(z2_bf,nullptr,DD, f_w1b,f_b1,1,l, FFF,DD, nullptr,ffh_bf, action,dof);
      k_mgemm<2><<<dim3(BB,2,4),256,0,stream>>>(ffh_bf,nullptr,FFF, f_w2b,f_b2,1,l, DD,FFF, x,nullptr, action,dof);
    }
    k_tag<<<TOK,256,0,stream>>>(x,tag,action,dof);
  }

  k_ln<<<TOK,256,0,stream>>>(x, nullptr, z_bf, nullptr);
  k_mgemm<0><<<dim3(1,16,VV/128),256,0,stream>>>(z_bf,nullptr,DD, lm_wb,lm_b,0,0, VV,DD, out,nullptr, nullptr,nullptr);
}

// Round 3
// 1139.133 us; speedup vs baseline: 2.8996x; 1.3073x over previous
//
#include <hip/hip_runtime.h>
#include <hip/hip_bf16.h>
#include <math.h>

#define BB   8
#define SS   256
#define DD   512
#define NHH  8
#define HDD  64
#define EE   4
#define LL   2
#define FFF  2048
#define RHH  256
#define VV   32000
#define MVV  2
#define TOK  (BB*SS)   // 2048

typedef __attribute__((ext_vector_type(8))) short bf16x8;
typedef __attribute__((ext_vector_type(4))) float f32x4;

// ---------------- helpers ----------------
__device__ __forceinline__ float wred_sum(float v){
#pragma unroll
  for(int o=32;o;o>>=1) v += __shfl_xor(v,o,64);
  return v;
}
__device__ __forceinline__ float block_sum(float v, float* sh){
  v = wred_sum(v);
  if((threadIdx.x&63)==0) sh[threadIdx.x>>6]=v;
  __syncthreads();
  float t = sh[0]+sh[1]+sh[2]+sh[3];
  __syncthreads();
  return t;
}
__device__ __forceinline__ float gelu_exact(float x){
  return 0.5f*x*(1.f+erff(x*0.70710678118654752f));
}
__device__ __forceinline__ unsigned short bfr(float f){
  union{float f; unsigned u;} c; c.f=f;
  unsigned u = c.u;
  return (unsigned short)((u + 0x7FFFu + ((u>>16)&1u)) >> 16);
}

// ---------------- cast all weights f32 -> bf16 in one kernel ----------------
__global__ void k_castall(const float* __restrict__ s0,const float* __restrict__ s1,
                          const float* __restrict__ s2,const float* __restrict__ s3,
                          const float* __restrict__ s4,const float* __restrict__ s5,
                          unsigned short* __restrict__ d0,unsigned short* __restrict__ d1,
                          unsigned short* __restrict__ d2,unsigned short* __restrict__ d3,
                          unsigned short* __restrict__ d4,unsigned short* __restrict__ d5){
  long i = (long)blockIdx.x*256 + threadIdx.x;
  const float* s; unsigned short* d; long o;
  if(i < 1572864L){ s=s0; d=d0; o=i; }
  else if(i < 2097152L){ s=s1; d=d1; o=i-1572864L; }
  else if(i < 3145728L){ s=s2; d=d2; o=i-2097152L; }
  else if(i < 5242880L){ s=s3; d=d3; o=i-3145728L; }
  else if(i < 7340032L){ s=s4; d=d4; o=i-5242880L; }
  else if(i < 11436032L){ s=s5; d=d5; o=i-7340032L; }
  else return;
  float4 v = ((const float4*)s)[o];
  ushort4 u; u.x=bfr(v.x); u.y=bfr(v.y); u.z=bfr(v.z); u.w=bfr(v.w);
  ((ushort4*)d)[o] = u;
}

// ---------------- embed + positional + input LN ----------------
__global__ void k_embed(const int* __restrict__ ids, const float* __restrict__ emb,
                        float* __restrict__ x){
  int tok = blockIdx.x;
  int s = tok & (SS-1);
  int tid = threadIdx.x;
  __shared__ float sh[4];
  int id = ids[tok];
  float v[2];
#pragma unroll
  for(int i=0;i<2;i++){
    int d = tid + i*256;
    float e = emb[(size_t)id*DD + d] * 22.627416997969522f; // sqrt(512)
    int j = d >> 1;
    float freq = expf((float)(2*j) * (-0.0179889460390160f)); // -ln(1e4)/512
    float arg = (float)s * freq;
    v[i] = e + ((d & 1) ? cosf(arg) : sinf(arg));
  }
  float m = block_sum(v[0]+v[1], sh) * (1.f/DD);
  float d0=v[0]-m, d1=v[1]-m;
  float var = block_sum(d0*d0+d1*d1, sh) * (1.f/DD);
  float inv = rsqrtf(var + 1e-5f);
  float* q = x + (size_t)tok*DD;
  q[tid] = d0*inv; q[tid+256] = d1*inv;
}

// ---------------- LN: optional f32 out, optional bf16 out, predicated ----------------
__global__ void k_ln(const float* __restrict__ in, float* __restrict__ outf,
                     unsigned short* __restrict__ outb, const int* __restrict__ dof){
  int tok = blockIdx.x;
  if(dof && !dof[tok>>8]) return;
  __shared__ float sh[4];
  int tid = threadIdx.x;
  const float* p = in + (size_t)tok*DD;
  float a0 = p[tid], a1 = p[tid+256];
  float m = block_sum(a0+a1, sh) * (1.f/DD);
  float d0=a0-m, d1=a1-m;
  float var = block_sum(d0*d0+d1*d1, sh) * (1.f/DD);
  float inv = rsqrtf(var + 1e-5f);
  float r0 = d0*inv, r1 = d1*inv;
  if(outf){ float* q = outf + (size_t)tok*DD; q[tid] = r0; q[tid+256] = r1; }
  if(outb){ unsigned short* q = outb + (size_t)tok*DD; q[tid] = bfr(r0); q[tid+256] = bfr(r1); }
}

// ---------------- fused summary + router ----------------
__global__ void k_sumrouter(const float* __restrict__ x,
                            const float* __restrict__ r_w1, const float* __restrict__ r_b1,
                            const float* __restrict__ r_w2, const float* __restrict__ r_b2,
                            const float* __restrict__ r_q,
                            int* __restrict__ action, int* __restrict__ dof,
                            int* __restrict__ visits, int* __restrict__ active, int step){
  int b = blockIdx.x; int tid = threadIdx.x;
  if(step==0 && tid==0){ active[b]=1; for(int e=0;e<EE;e++) visits[b*EE+e]=0; }
  __shared__ float ssum[DD];
  __shared__ float hid[RHH];
  __shared__ float lg[EE+1];
  const float* xb = x + (size_t)b*SS*DD;
  float s0=0.f, s1=0.f;
  for(int tt=0; tt<SS; tt++){
    s0 += xb[(size_t)tt*DD + tid];
    s1 += xb[(size_t)tt*DD + tid + 256];
  }
  ssum[tid] = s0*(1.f/SS); ssum[tid+256] = s1*(1.f/SS);
  __syncthreads();
  float acc = r_b1[tid];
  const float4* wr4 = (const float4*)(r_w1 + (size_t)tid*DD);
  for(int d4=0; d4<DD/4; d4++){
    float4 wv = wr4[d4];
    float4 sv = *(const float4*)&ssum[d4*4];
    acc += wv.x*sv.x + wv.y*sv.y + wv.z*sv.z + wv.w*sv.w;
  }
  hid[tid] = gelu_exact(acc);
  __syncthreads();
  if(tid < EE+1){
    const float* w2 = r_w2 + (size_t)tid*RHH;
    float a = r_b2[tid] + r_q[tid];
    for(int j=0;j<RHH;j++) a += hid[j]*w2[j];
    lg[tid]=a;
  }
  __syncthreads();
  if(tid==0){
    float m=0.f; for(int k=0;k<EE+1;k++) m+=lg[k]; m *= (1.f/(EE+1));
    float v=0.f; for(int k=0;k<EE+1;k++){float d=lg[k]-m; v+=d*d;} v *= (1.f/(EE+1));
    float inv = rsqrtf(v+1e-5f);
    float best=-1e38f; int bi=0;
    for(int k=0;k<EE+1;k++){
      float fl = (lg[k]-m)*inv;
      fl = fminf(fmaxf(fl,-10.f),10.f);
      if(k<EE && visits[b*EE+k]>=MVV) fl = -1e38f;
      if(fl > best){best=fl; bi=k;}
    }
    int dd = (active[b] && bi<EE) ? 1 : 0;
    action[b]=bi; dof[b]=dd;
    if(dd) visits[b*EE+bi]++;
    active[b]=dd;
  }
}

// ---------------- bf16 MFMA GEMM, 128x128 tile, BK=64 ----------------
// EPI: 0 = store (Cf and/or Cb), 1 = gelu -> Cb, 2 = Cf += (+ tag if tagp)
template<int EPI>
__global__ __launch_bounds__(256)
void k_mgemm(const unsigned short* __restrict__ A1, const unsigned short* __restrict__ A2,
             int ksplit,
             const unsigned short* __restrict__ Wb, const float* __restrict__ bb,
             int wsel, int l, int N, int K,
             float* __restrict__ Cf, unsigned short* __restrict__ Cb,
             const float* __restrict__ tagp,
             const int* __restrict__ action, const int* __restrict__ dof){
  int b = blockIdx.x;
  if(dof && !dof[b]) return;
  const unsigned short* W = Wb; const float* bias = bb;
  if(wsel){ size_t o = (size_t)(action[b]*LL + l); W += o*(size_t)N*K; bias += o*N; }
  int rowbase = b*SS + blockIdx.y*128;
  int colbase = blockIdx.z*128;
  __shared__ unsigned short sA[128*64];
  __shared__ unsigned short sW[128*64];
  int t = threadIdx.x;
  int lane = t & 63;
  int w = t >> 6, wr = w >> 1, wc = w & 1;
  int sr = t >> 3;          // 0..31
  int ss8 = t & 7;          // 16B slot

  f32x4 acc[4][4];
#pragma unroll
  for(int m=0;m<4;m++)
#pragma unroll
    for(int n=0;n<4;n++) acc[m][n] = (f32x4){0.f,0.f,0.f,0.f};

  for(int k0 = 0; k0 < K; k0 += 64){
    const unsigned short* Ab; int kb0, kstr;
    if(k0 < ksplit){ Ab = A1; kb0 = k0;          kstr = ksplit; }
    else           { Ab = A2; kb0 = k0 - ksplit; kstr = K - ksplit; }
#pragma unroll
    for(int i = 0; i < 4; i++){
      int r  = i*32 + sr;
      int ce = ((ss8<<4) ^ ((r&7)<<4)) >> 1;
      const unsigned short* gp = Ab + (size_t)(rowbase + r)*kstr + kb0 + ce;
      __builtin_amdgcn_global_load_lds((const __attribute__((address_space(1))) void*)gp,
          (__attribute__((address_space(3))) void*)(sA + i*2048 + t*8), 16, 0, 0);
      const unsigned short* gw = W + (size_t)(colbase + r)*K + k0 + ce;
      __builtin_amdgcn_global_load_lds((const __attribute__((address_space(1))) void*)gw,
          (__attribute__((address_space(3))) void*)(sW + i*2048 + t*8), 16, 0, 0);
    }
    __syncthreads();
#pragma unroll
    for(int ks = 0; ks < 2; ks++){
      bf16x8 af[4], wf[4];
#pragma unroll
      for(int m = 0; m < 4; m++){
        int r = wr*64 + m*16 + (lane & 15);
        af[m] = *(const bf16x8*)((const char*)sA + r*128 + (((((lane>>4)<<4)|(ks<<6))) ^ ((r&7)<<4)));
      }
#pragma unroll
      for(int n = 0; n < 4; n++){
        int r = wc*64 + n*16 + (lane & 15);
        wf[n] = *(const bf16x8*)((const char*)sW + r*128 + (((((lane>>4)<<4)|(ks<<6))) ^ ((r&7)<<4)));
      }
#pragma unroll
      for(int m = 0; m < 4; m++)
#pragma unroll
        for(int n = 0; n < 4; n++)
          acc[m][n] = __builtin_amdgcn_mfma_f32_16x16x32_bf16(af[m], wf[n], acc[m][n], 0, 0, 0);
    }
    __syncthreads();
  }
  int orow0 = rowbase + wr*64 + ((lane >> 4) << 2);
  int ocol0 = colbase + wc*64 + (lane & 15);
#pragma unroll
  for(int m = 0; m < 4; m++){
#pragma unroll
    for(int n = 0; n < 4; n++){
      int col = ocol0 + n*16;
      float bv = bias[col];
      float tg = 0.f;
      if(EPI == 2 && tagp) tg = tagp[(size_t)action[b]*DD + col];
#pragma unroll
      for(int j = 0; j < 4; j++){
        int row = orow0 + m*16 + j;
        size_t idx = (size_t)row*N + col;
        float v = acc[m][n][j] + bv;
        if(EPI == 0){ if(Cf) Cf[idx] = v; if(Cb) Cb[idx] = bfr(v); }
        else if(EPI == 1){ Cb[idx] = bfr(gelu_exact(v)); }
        else { Cf[idx] += v + tg; }
      }
    }
  }
}

// ---------------- fused attention: softmax(QK^T/8) @ V, bf16 MFMA ----------------
// grid (BB*NHH, SS/64), 256 threads. qkv bf16 [TOK][1536]. attno bf16 [TOK][512].
__global__ __launch_bounds__(256)
void k_attn(const unsigned short* __restrict__ qkv, unsigned short* __restrict__ attno,
            const int* __restrict__ dof){
  int bh = blockIdx.x; int b = bh>>3, h = bh&7;
  if(!dof[b]) return;
  int q0 = blockIdx.y*64;
  __shared__ unsigned short sK[256*64];   // 32KB; reused as P after scores
  __shared__ unsigned short sVT[64*256];  // 32KB, V transposed [d][k]
  int t = threadIdx.x, l = t&63, w = t>>6;
  const unsigned short* qbase = qkv + (size_t)b*SS*1536;

  // stage K via global_load_lds (8 issues of 32 rows x 128B), XOR swizzled source
  {
    int sr = t>>3, s8 = t&7;
#pragma unroll
    for(int i=0;i<8;i++){
      int r = i*32 + sr;
      int ce = ((s8<<4) ^ ((r&7)<<4)) >> 1;
      const unsigned short* gp = qbase + (size_t)r*1536 + 512 + h*64 + ce;
      __builtin_amdgcn_global_load_lds((const __attribute__((address_space(1))) void*)gp,
          (__attribute__((address_space(3))) void*)(sK + i*2048 + t*8), 16, 0, 0);
    }
  }
  // stage V transposed: VT[d][k], swizzled byte = d*512 + ((k*2)^((d&7)<<4))
  {
    int kt0 = t>>2, dg = (t&3)*16;
#pragma unroll
    for(int i=0;i<4;i++){
      int kt = i*64 + kt0;
      const unsigned short* gp = qbase + (size_t)kt*1536 + 1024 + h*64 + dg;
      bf16x8 v0 = *(const bf16x8*)gp;
      bf16x8 v1 = *(const bf16x8*)(gp+8);
#pragma unroll
      for(int e=0;e<8;e++){
        int d  = dg+e;
        *(unsigned short*)((char*)sVT + d*512  + ((kt*2) ^ ((d&7)<<4)))  = (unsigned short)v0[e];
        int d2 = dg+8+e;
        *(unsigned short*)((char*)sVT + d2*512 + ((kt*2) ^ ((d2&7)<<4))) = (unsigned short)v1[e];
      }
    }
  }
  // Q fragments straight from global (tiny): row = q0 + w*16 + (l&15)
  bf16x8 qf[2];
  {
    const unsigned short* qrow = qbase + (size_t)(q0 + w*16 + (l&15))*1536 + h*64;
    qf[0] = *(const bf16x8*)(qrow + ((l>>4)<<3));
    qf[1] = *(const bf16x8*)(qrow + ((l>>4)<<3) + 32);
  }
  __syncthreads();

  // scores: 16 q-rows per wave x 256 keys
  f32x4 sacc[16];
#pragma unroll
  for(int kb=0;kb<16;kb++) sacc[kb] = (f32x4){0.f,0.f,0.f,0.f};
#pragma unroll
  for(int kb=0;kb<16;kb++){
    int rk = kb*16 + (l&15);
#pragma unroll
    for(int ks=0;ks<2;ks++){
      bf16x8 kf = *(const bf16x8*)((const char*)sK + rk*128 + (((((l>>4)<<4)|(ks<<6))) ^ ((rk&7)<<4)));
      sacc[kb] = __builtin_amdgcn_mfma_f32_16x16x32_bf16(qf[ks], kf, sacc[kb], 0, 0, 0);
    }
  }
  // softmax over keys (scale 1/8); C layout: row=(l>>4)*4+j, col=l&15
  float rden[4];
#pragma unroll
  for(int j=0;j<4;j++){
    float m = -1e38f;
#pragma unroll
    for(int kb=0;kb<16;kb++) m = fmaxf(m, sacc[kb][j]);
#pragma unroll
    for(int o=1;o<16;o<<=1) m = fmaxf(m, __shfl_xor(m,o,64));
    m *= 0.125f;
    float s = 0.f;
#pragma unroll
    for(int kb=0;kb<16;kb++){
      float e = expf(sacc[kb][j]*0.125f - m);
      sacc[kb][j] = e; s += e;
    }
#pragma unroll
    for(int o=1;o<16;o<<=1) s += __shfl_xor(s,o,64);
    rden[j] = 1.f/s;
  }
  __syncthreads();   // all K reads done before P overwrites sK

  // write P (bf16) into per-wave region of sK
  char* sP = (char*)sK + w*8192;
#pragma unroll
  for(int kb=0;kb<16;kb++){
    int k = kb*16 + (l&15);
#pragma unroll
    for(int j=0;j<4;j++){
      int qr = ((l>>4)<<2) + j;
      *(unsigned short*)(sP + qr*512 + ((k*2) ^ ((qr&7)<<4))) = bfr(sacc[kb][j]);
    }
  }
  __syncthreads();

  // PV: o[16q x 64d] += P[16q x 256k] @ V[256k x 64d]
  f32x4 oacc[4];
#pragma unroll
  for(int df=0;df<4;df++) oacc[df] = (f32x4){0.f,0.f,0.f,0.f};
#pragma unroll
  for(int kstep=0;kstep<8;kstep++){
    bf16x8 pa = *(const bf16x8*)(sP + (l&15)*512 + ((((kstep<<6)|((l>>4)<<4))) ^ ((l&7)<<4)));
#pragma unroll
    for(int df=0;df<4;df++){
      int d = df*16 + (l&15);
      bf16x8 vb = *(const bf16x8*)((char*)sVT + d*512 + ((((kstep<<6)|((l>>4)<<4))) ^ ((d&7)<<4)));
      oacc[df] = __builtin_amdgcn_mfma_f32_16x16x32_bf16(pa, vb, oacc[df], 0, 0, 0);
    }
  }
  // write attno (bf16), dividing by softmax denom
  int orow0 = b*SS + q0 + w*16 + ((l>>4)<<2);
#pragma unroll
  for(int df=0;df<4;df++){
    int col = h*64 + df*16 + (l&15);
#pragma unroll
    for(int j=0;j<4;j++)
      attno[(size_t)(orow0+j)*DD + col] = bfr(oacc[df][j]*rden[j]);
  }
}

// ---------------- gated residual + LN2 fused ----------------
// x += LN(z + sigmoid(g)*ao); z2_bf = LN(x_new)
__global__ void k_gateres_ln(const float* __restrict__ z, const float* __restrict__ ao,
                             const float* __restrict__ g, float* __restrict__ x,
                             unsigned short* __restrict__ z2b, const int* __restrict__ dof){
  int tok = blockIdx.x; if(!dof[tok>>8]) return;
  __shared__ float sh[4];
  int tid=threadIdx.x;
  size_t base=(size_t)tok*DD;
  float zz0=z[base+tid],     aa0=ao[base+tid],     gg0=g[base+tid];
  float zz1=z[base+tid+256], aa1=ao[base+tid+256], gg1=g[base+tid+256];
  float t0 = zz0 + aa0/(1.f+expf(-gg0));
  float t1 = zz1 + aa1/(1.f+expf(-gg1));
  float m = block_sum(t0+t1,sh)*(1.f/DD);
  float d0=t0-m, d1=t1-m;
  float var=block_sum(d0*d0+d1*d1,sh)*(1.f/DD);
  float inv=rsqrtf(var+1e-5f);
  float xn0 = x[base+tid]     + d0*inv;
  float xn1 = x[base+tid+256] + d1*inv;
  x[base+tid] = xn0; x[base+tid+256] = xn1;
  float m2 = block_sum(xn0+xn1,sh)*(1.f/DD);
  float e0=xn0-m2, e1=xn1-m2;
  float var2=block_sum(e0*e0+e1*e1,sh)*(1.f/DD);
  float inv2=rsqrtf(var2+1e-5f);
  z2b[base+tid] = bfr(e0*inv2); z2b[base+tid+256] = bfr(e1*inv2);
}

// ---------------- host launcher ----------------
extern "C" void kernel_launch(void* const* d_in, const int* in_sizes, int n_in,
                              void* d_out, int out_size, void* d_ws, size_t ws_size,
                              hipStream_t stream){
  const int*   ids   = (const int*)d_in[0];
  const float* emb   = (const float*)d_in[1];
  const float* r_w1  = (const float*)d_in[2];
  const float* r_b1  = (const float*)d_in[3];
  const float* r_w2  = (const float*)d_in[4];
  const float* r_b2  = (const float*)d_in[5];
  const float* r_q   = (const float*)d_in[6];
  const float* in_w  = (const float*)d_in[7];
  const float* in_b  = (const float*)d_in[8];
  const float* out_w = (const float*)d_in[9];
  const float* out_b = (const float*)d_in[10];
  const float* gate_w= (const float*)d_in[11];
  const float* gate_b= (const float*)d_in[12];
  const float* f_w1  = (const float*)d_in[13];
  const float* f_b1  = (const float*)d_in[14];
  const float* f_w2  = (const float*)d_in[15];
  const float* f_b2  = (const float*)d_in[16];
  const float* tag   = (const float*)d_in[17];
  const float* lm_w  = (const float*)d_in[18];
  const float* lm_b  = (const float*)d_in[19];
  float* out = (float*)d_out;
  float* ws  = (float*)d_ws;

  const size_t M = (size_t)TOK*DD;   // 1,048,576
  float* x      = ws;            // 1M f32
  float* z      = ws + 1*M;      // 1M f32
  float* ao     = ws + 2*M;      // 1M f32
  float* gtmp   = ws + 3*M;      // 1M f32
  int*   ipool  = (int*)(ws + 4*M);
  int* action = ipool; int* dof = ipool+BB; int* active = ipool+2*BB; int* visits = ipool+3*BB;

  unsigned short* ub = (unsigned short*)(ws + 4*M + 64);
  unsigned short* z_bf     = ub;          // 1M
  unsigned short* ao_bf    = ub + 1*M;    // 1M
  unsigned short* z2_bf    = ub + 2*M;    // 1M
  unsigned short* attno_bf = ub + 3*M;    // 1M
  unsigned short* qkv_bf   = ub + 4*M;    // 3M
  unsigned short* ffh_bf   = ub + 7*M;    // 4M
  unsigned short* wb = ub + 11*M;
  unsigned short* in_wb   = wb;
  unsigned short* out_wb  = in_wb  + (size_t)EE*LL*3*DD*DD;
  unsigned short* gate_wb = out_wb + (size_t)EE*LL*DD*DD;
  unsigned short* f_w1b   = gate_wb+ (size_t)EE*LL*DD*2*DD;
  unsigned short* f_w2b   = f_w1b  + (size_t)EE*LL*FFF*DD;
  unsigned short* lm_wb   = f_w2b  + (size_t)EE*LL*DD*FFF;

  k_castall<<<44672,256,0,stream>>>(in_w,out_w,gate_w,f_w1,f_w2,lm_w,
                                    in_wb,out_wb,gate_wb,f_w1b,f_w2b,lm_wb);

  k_embed<<<TOK,256,0,stream>>>(ids, emb, x);

  for(int step=0; step<3; step++){
    k_sumrouter<<<BB,256,0,stream>>>(x,r_w1,r_b1,r_w2,r_b2,r_q,action,dof,visits,active,step);
    for(int l=0; l<LL; l++){
      k_ln<<<TOK,256,0,stream>>>(x, z, z_bf, dof);
      k_mgemm<0><<<dim3(BB,2,12),256,0,stream>>>(z_bf,nullptr,DD, in_wb,in_b,1,l, 3*DD,DD, nullptr,qkv_bf, nullptr, action,dof);
      k_attn<<<dim3(BB*NHH,4),256,0,stream>>>(qkv_bf, attno_bf, dof);
      k_mgemm<0><<<dim3(BB,2,4),256,0,stream>>>(attno_bf,nullptr,DD, out_wb,out_b,1,l, DD,DD, ao,ao_bf, nullptr, action,dof);
      k_mgemm<0><<<dim3(BB,2,4),256,0,stream>>>(z_bf,ao_bf,DD, gate_wb,gate_b,1,l, DD,2*DD, gtmp,nullptr, nullptr, action,dof);
      k_gateres_ln<<<TOK,256,0,stream>>>(z,ao,gtmp,x,z2_bf,dof);
      k_mgemm<1><<<dim3(BB,2,16),256,0,stream>>>(z2_bf,nullptr,DD, f_w1b,f_b1,1,l, FFF,DD, nullptr,ffh_bf, nullptr, action,dof);
      k_mgemm<2><<<dim3(BB,2,4),256,0,stream>>>(ffh_bf,nullptr,FFF, f_w2b,f_b2,1,l, DD,FFF, x,nullptr, (l==LL-1)?tag:nullptr, action,dof);
    }
  }

  k_ln<<<TOK,256,0,stream>>>(x, nullptr, z_bf, nullptr);
  k_mgemm<0><<<dim3(1,16,VV/128),256,0,stream>>>(z_bf,nullptr,DD, lm_wb,lm_b,0,0, VV,DD, out,nullptr, nullptr, nullptr,nullptr);
}

// Round 4
// 1092.350 us; speedup vs baseline: 3.0238x; 1.0428x over previous
//
#include <hip/hip_runtime.h>
#include <hip/hip_bf16.h>
#include <math.h>

#define BB   8
#define SS   256
#define DD   512
#define NHH  8
#define HDD  64
#define EE   4
#define LL   2
#define FFF  2048
#define RHH  256
#define VV   32000
#define MVV  2
#define TOK  (BB*SS)   // 2048
#define CASTN4 11436032L
#define CASTBLK 44672

typedef __attribute__((ext_vector_type(8))) short bf16x8;
typedef __attribute__((ext_vector_type(4))) float f32x4;

// ---------------- helpers ----------------
__device__ __forceinline__ float wred_sum(float v){
#pragma unroll
  for(int o=32;o;o>>=1) v += __shfl_xor(v,o,64);
  return v;
}
__device__ __forceinline__ float block_sum(float v, float* sh){
  v = wred_sum(v);
  if((threadIdx.x&63)==0) sh[threadIdx.x>>6]=v;
  __syncthreads();
  float t = sh[0]+sh[1]+sh[2]+sh[3];
  __syncthreads();
  return t;
}
__device__ __forceinline__ float gelu_exact(float x){
  return 0.5f*x*(1.f+erff(x*0.70710678118654752f));
}
__device__ __forceinline__ unsigned short bfr(float f){
  union{float f; unsigned u;} c; c.f=f;
  unsigned u = c.u;
  return (unsigned short)((u + 0x7FFFu + ((u>>16)&1u)) >> 16);
}

// ---------------- fused: weight casts (blocks < CASTBLK) + embed+PE+LN ----------------
__global__ void k_preproc(const float* __restrict__ s0,const float* __restrict__ s1,
                          const float* __restrict__ s2,const float* __restrict__ s3,
                          const float* __restrict__ s4,const float* __restrict__ s5,
                          unsigned short* __restrict__ d0,unsigned short* __restrict__ d1,
                          unsigned short* __restrict__ d2,unsigned short* __restrict__ d3,
                          unsigned short* __restrict__ d4,unsigned short* __restrict__ d5,
                          const int* __restrict__ ids, const float* __restrict__ emb,
                          float* __restrict__ x){
  __shared__ float sh[4];
  if(blockIdx.x < CASTBLK){
    long i = (long)blockIdx.x*256 + threadIdx.x;
    const float* s; unsigned short* d; long o;
    if(i < 1572864L){ s=s0; d=d0; o=i; }
    else if(i < 2097152L){ s=s1; d=d1; o=i-1572864L; }
    else if(i < 3145728L){ s=s2; d=d2; o=i-2097152L; }
    else if(i < 5242880L){ s=s3; d=d3; o=i-3145728L; }
    else if(i < 7340032L){ s=s4; d=d4; o=i-5242880L; }
    else { s=s5; d=d5; o=i-7340032L; }
    float4 v = ((const float4*)s)[o];
    ushort4 u; u.x=bfr(v.x); u.y=bfr(v.y); u.z=bfr(v.z); u.w=bfr(v.w);
    ((ushort4*)d)[o] = u;
    return;
  }
  int tok = blockIdx.x - CASTBLK;
  int s = tok & (SS-1);
  int tid = threadIdx.x;
  int id = ids[tok];
  float v[2];
#pragma unroll
  for(int i=0;i<2;i++){
    int d = tid + i*256;
    float e = emb[(size_t)id*DD + d] * 22.627416997969522f; // sqrt(512)
    int j = d >> 1;
    float freq = expf((float)(2*j) * (-0.0179889460390160f)); // -ln(1e4)/512
    float arg = (float)s * freq;
    v[i] = e + ((d & 1) ? cosf(arg) : sinf(arg));
  }
  float m = block_sum(v[0]+v[1], sh) * (1.f/DD);
  float dd0=v[0]-m, dd1=v[1]-m;
  float var = block_sum(dd0*dd0+dd1*dd1, sh) * (1.f/DD);
  float inv = rsqrtf(var + 1e-5f);
  float* q = x + (size_t)tok*DD;
  q[tid] = dd0*inv; q[tid+256] = dd1*inv;
}

// ---------------- LN: optional f32 out, optional bf16 out, predicated ----------------
__global__ void k_ln(const float* __restrict__ in, float* __restrict__ outf,
                     unsigned short* __restrict__ outb, const int* __restrict__ dof){
  int tok = blockIdx.x;
  if(dof && !dof[tok>>8]) return;
  __shared__ float sh[4];
  int tid = threadIdx.x;
  const float* p = in + (size_t)tok*DD;
  float a0 = p[tid], a1 = p[tid+256];
  float m = block_sum(a0+a1, sh) * (1.f/DD);
  float d0=a0-m, d1=a1-m;
  float var = block_sum(d0*d0+d1*d1, sh) * (1.f/DD);
  float inv = rsqrtf(var + 1e-5f);
  float r0 = d0*inv, r1 = d1*inv;
  if(outf){ float* q = outf + (size_t)tok*DD; q[tid] = r0; q[tid+256] = r1; }
  if(outb){ unsigned short* q = outb + (size_t)tok*DD; q[tid] = bfr(r0); q[tid+256] = bfr(r1); }
}

// ---------------- fused summary + router ----------------
__global__ void k_sumrouter(const float* __restrict__ x,
                            const float* __restrict__ r_w1, const float* __restrict__ r_b1,
                            const float* __restrict__ r_w2, const float* __restrict__ r_b2,
                            const float* __restrict__ r_q,
                            int* __restrict__ action, int* __restrict__ dof,
                            int* __restrict__ visits, int* __restrict__ active, int step){
  int b = blockIdx.x; int tid = threadIdx.x;
  if(step==0 && tid==0){ active[b]=1; for(int e=0;e<EE;e++) visits[b*EE+e]=0; }
  __shared__ float ssum[DD];
  __shared__ float hid[RHH];
  __shared__ float lg[EE+1];
  const float* xb = x + (size_t)b*SS*DD;
  float s0=0.f, s1=0.f;
  for(int tt=0; tt<SS; tt++){
    s0 += xb[(size_t)tt*DD + tid];
    s1 += xb[(size_t)tt*DD + tid + 256];
  }
  ssum[tid] = s0*(1.f/SS); ssum[tid+256] = s1*(1.f/SS);
  __syncthreads();
  float acc = r_b1[tid];
  const float4* wr4 = (const float4*)(r_w1 + (size_t)tid*DD);
  for(int d4=0; d4<DD/4; d4++){
    float4 wv = wr4[d4];
    float4 sv = *(const float4*)&ssum[d4*4];
    acc += wv.x*sv.x + wv.y*sv.y + wv.z*sv.z + wv.w*sv.w;
  }
  hid[tid] = gelu_exact(acc);
  __syncthreads();
  if(tid < EE+1){
    const float* w2 = r_w2 + (size_t)tid*RHH;
    float a = r_b2[tid] + r_q[tid];
    for(int j=0;j<RHH;j++) a += hid[j]*w2[j];
    lg[tid]=a;
  }
  __syncthreads();
  if(tid==0){
    float m=0.f; for(int k=0;k<EE+1;k++) m+=lg[k]; m *= (1.f/(EE+1));
    float v=0.f; for(int k=0;k<EE+1;k++){float d=lg[k]-m; v+=d*d;} v *= (1.f/(EE+1));
    float inv = rsqrtf(v+1e-5f);
    float best=-1e38f; int bi=0;
    for(int k=0;k<EE+1;k++){
      float fl = (lg[k]-m)*inv;
      fl = fminf(fmaxf(fl,-10.f),10.f);
      if(k<EE && visits[b*EE+k]>=MVV) fl = -1e38f;
      if(fl > best){best=fl; bi=k;}
    }
    int dd = (active[b] && bi<EE) ? 1 : 0;
    action[b]=bi; dof[b]=dd;
    if(dd) visits[b*EE+bi]++;
    active[b]=dd;
  }
}

// ---------------- bf16 MFMA GEMM, 128x128 tile, BK=64, 2-phase double-buffered ----------------
// EPI: 0 = store (Cf and/or Cb), 1 = gelu -> Cb, 2 = Cf += (+ tag if tagp)
template<int EPI>
__global__ __launch_bounds__(256)
void k_mgemm(const unsigned short* __restrict__ A1, const unsigned short* __restrict__ A2,
             int ksplit,
             const unsigned short* __restrict__ Wb, const float* __restrict__ bb,
             int wsel, int l, int N, int K,
             float* __restrict__ Cf, unsigned short* __restrict__ Cb,
             const float* __restrict__ tagp,
             const int* __restrict__ action, const int* __restrict__ dof){
  int b = blockIdx.x;
  if(dof && !dof[b]) return;
  const unsigned short* W = Wb; const float* bias = bb;
  if(wsel){ size_t o = (size_t)(action[b]*LL + l); W += o*(size_t)N*K; bias += o*N; }
  int rowbase = b*SS + blockIdx.y*128;
  int colbase = blockIdx.z*128;
  __shared__ unsigned short sA[2*128*64];   // 32KB
  __shared__ unsigned short sW[2*128*64];   // 32KB
  int t = threadIdx.x;
  int lane = t & 63;
  int w = t >> 6, wr = w >> 1, wc = w & 1;
  int sr = t >> 3;          // 0..31
  int ss8 = t & 7;          // 16B slot

  f32x4 acc[4][4];
#pragma unroll
  for(int m=0;m<4;m++)
#pragma unroll
    for(int n=0;n<4;n++) acc[m][n] = (f32x4){0.f,0.f,0.f,0.f};

  // stage one 128x64 tile pair into buffer `buf` (8 global_load_lds per wave)
  auto STAGE = [&](int buf, int k0){
    const unsigned short* Ab; int kb0, kstr;
    if(k0 < ksplit){ Ab = A1; kb0 = k0;          kstr = ksplit; }
    else           { Ab = A2; kb0 = k0 - ksplit; kstr = K - ksplit; }
    unsigned short* dA = sA + buf*8192;
    unsigned short* dW = sW + buf*8192;
#pragma unroll
    for(int i = 0; i < 4; i++){
      int r  = i*32 + sr;
      int ce = ((ss8<<4) ^ ((r&7)<<4)) >> 1;
      const unsigned short* gp = Ab + (size_t)(rowbase + r)*kstr + kb0 + ce;
      __builtin_amdgcn_global_load_lds((const __attribute__((address_space(1))) void*)gp,
          (__attribute__((address_space(3))) void*)(dA + i*2048 + t*8), 16, 0, 0);
      const unsigned short* gw = W + (size_t)(colbase + r)*K + k0 + ce;
      __builtin_amdgcn_global_load_lds((const __attribute__((address_space(1))) void*)gw,
          (__attribute__((address_space(3))) void*)(dW + i*2048 + t*8), 16, 0, 0);
    }
  };

  STAGE(0, 0);
  int cur = 0;
  for(int k0 = 0; k0 < K; k0 += 64){
    if(k0 + 64 < K){
      STAGE(cur^1, k0+64);                               // prefetch next tile
      asm volatile("s_waitcnt vmcnt(8)" ::: "memory");   // current tile landed; next in flight
    } else {
      asm volatile("s_waitcnt vmcnt(0)" ::: "memory");
    }
    __builtin_amdgcn_s_barrier();                        // no vmcnt(0) drain here
    __builtin_amdgcn_sched_barrier(0);
    const unsigned short* bA = sA + cur*8192;
    const unsigned short* bW = sW + cur*8192;
#pragma unroll
    for(int ks = 0; ks < 2; ks++){
      bf16x8 af[4], wf[4];
#pragma unroll
      for(int m = 0; m < 4; m++){
        int r = wr*64 + m*16 + (lane & 15);
        af[m] = *(const bf16x8*)((const char*)bA + r*128 + (((((lane>>4)<<4)|(ks<<6))) ^ ((r&7)<<4)));
      }
#pragma unroll
      for(int n = 0; n < 4; n++){
        int r = wc*64 + n*16 + (lane & 15);
        wf[n] = *(const bf16x8*)((const char*)bW + r*128 + (((((lane>>4)<<4)|(ks<<6))) ^ ((r&7)<<4)));
      }
#pragma unroll
      for(int m = 0; m < 4; m++)
#pragma unroll
        for(int n = 0; n < 4; n++)
          acc[m][n] = __builtin_amdgcn_mfma_f32_16x16x32_bf16(af[m], wf[n], acc[m][n], 0, 0, 0);
    }
    asm volatile("s_waitcnt lgkmcnt(0)" ::: "memory");   // my reads of buf[cur] done
    __builtin_amdgcn_s_barrier();                        // everyone's reads done -> buf reusable
    cur ^= 1;
  }
  int orow0 = rowbase + wr*64 + ((lane >> 4) << 2);
  int ocol0 = colbase + wc*64 + (lane & 15);
#pragma unroll
  for(int m = 0; m < 4; m++){
#pragma unroll
    for(int n = 0; n < 4; n++){
      int col = ocol0 + n*16;
      float bv = bias[col];
      float tg = 0.f;
      if(EPI == 2 && tagp) tg = tagp[(size_t)action[b]*DD + col];
#pragma unroll
      for(int j = 0; j < 4; j++){
        int row = orow0 + m*16 + j;
        size_t idx = (size_t)row*N + col;
        float v = acc[m][n][j] + bv;
        if(EPI == 0){ if(Cf) Cf[idx] = v; if(Cb) Cb[idx] = bfr(v); }
        else if(EPI == 1){ Cb[idx] = bfr(gelu_exact(v)); }
        else { Cf[idx] += v + tg; }
      }
    }
  }
}

// ---------------- fused attention: softmax(QK^T/8) @ V, bf16 MFMA ----------------
__global__ __launch_bounds__(256)
void k_attn(const unsigned short* __restrict__ qkv, unsigned short* __restrict__ attno,
            const int* __restrict__ dof){
  int bh = blockIdx.x; int b = bh>>3, h = bh&7;
  if(!dof[b]) return;
  int q0 = blockIdx.y*64;
  __shared__ unsigned short sK[256*64];   // 32KB; reused as P after scores
  __shared__ unsigned short sVT[64*256];  // 32KB, V transposed [d][k]
  int t = threadIdx.x, l = t&63, w = t>>6;
  const unsigned short* qbase = qkv + (size_t)b*SS*1536;

  {
    int sr = t>>3, s8 = t&7;
#pragma unroll
    for(int i=0;i<8;i++){
      int r = i*32 + sr;
      int ce = ((s8<<4) ^ ((r&7)<<4)) >> 1;
      const unsigned short* gp = qbase + (size_t)r*1536 + 512 + h*64 + ce;
      __builtin_amdgcn_global_load_lds((const __attribute__((address_space(1))) void*)gp,
          (__attribute__((address_space(3))) void*)(sK + i*2048 + t*8), 16, 0, 0);
    }
  }
  {
    int kt0 = t>>2, dg = (t&3)*16;
#pragma unroll
    for(int i=0;i<4;i++){
      int kt = i*64 + kt0;
      const unsigned short* gp = qbase + (size_t)kt*1536 + 1024 + h*64 + dg;
      bf16x8 v0 = *(const bf16x8*)gp;
      bf16x8 v1 = *(const bf16x8*)(gp+8);
#pragma unroll
      for(int e=0;e<8;e++){
        int d  = dg+e;
        *(unsigned short*)((char*)sVT + d*512  + ((kt*2) ^ ((d&7)<<4)))  = (unsigned short)v0[e];
        int d2 = dg+8+e;
        *(unsigned short*)((char*)sVT + d2*512 + ((kt*2) ^ ((d2&7)<<4))) = (unsigned short)v1[e];
      }
    }
  }
  bf16x8 qf[2];
  {
    const unsigned short* qrow = qbase + (size_t)(q0 + w*16 + (l&15))*1536 + h*64;
    qf[0] = *(const bf16x8*)(qrow + ((l>>4)<<3));
    qf[1] = *(const bf16x8*)(qrow + ((l>>4)<<3) + 32);
  }
  __syncthreads();

  f32x4 sacc[16];
#pragma unroll
  for(int kb=0;kb<16;kb++) sacc[kb] = (f32x4){0.f,0.f,0.f,0.f};
#pragma unroll
  for(int kb=0;kb<16;kb++){
    int rk = kb*16 + (l&15);
#pragma unroll
    for(int ks=0;ks<2;ks++){
      bf16x8 kf = *(const bf16x8*)((const char*)sK + rk*128 + (((((l>>4)<<4)|(ks<<6))) ^ ((rk&7)<<4)));
      sacc[kb] = __builtin_amdgcn_mfma_f32_16x16x32_bf16(qf[ks], kf, sacc[kb], 0, 0, 0);
    }
  }
  float rden[4];
#pragma unroll
  for(int j=0;j<4;j++){
    float m = -1e38f;
#pragma unroll
    for(int kb=0;kb<16;kb++) m = fmaxf(m, sacc[kb][j]);
#pragma unroll
    for(int o=1;o<16;o<<=1) m = fmaxf(m, __shfl_xor(m,o,64));
    m *= 0.125f;
    float s = 0.f;
#pragma unroll
    for(int kb=0;kb<16;kb++){
      float e = expf(sacc[kb][j]*0.125f - m);
      sacc[kb][j] = e; s += e;
    }
#pragma unroll
    for(int o=1;o<16;o<<=1) s += __shfl_xor(s,o,64);
    rden[j] = 1.f/s;
  }
  __syncthreads();

  char* sP = (char*)sK + w*8192;
#pragma unroll
  for(int kb=0;kb<16;kb++){
    int k = kb*16 + (l&15);
#pragma unroll
    for(int j=0;j<4;j++){
      int qr = ((l>>4)<<2) + j;
      *(unsigned short*)(sP + qr*512 + ((k*2) ^ ((qr&7)<<4))) = bfr(sacc[kb][j]);
    }
  }
  __syncthreads();

  f32x4 oacc[4];
#pragma unroll
  for(int df=0;df<4;df++) oacc[df] = (f32x4){0.f,0.f,0.f,0.f};
#pragma unroll
  for(int kstep=0;kstep<8;kstep++){
    bf16x8 pa = *(const bf16x8*)(sP + (l&15)*512 + ((((kstep<<6)|((l>>4)<<4))) ^ ((l&7)<<4)));
#pragma unroll
    for(int df=0;df<4;df++){
      int d = df*16 + (l&15);
      bf16x8 vb = *(const bf16x8*)((char*)sVT + d*512 + ((((kstep<<6)|((l>>4)<<4))) ^ ((d&7)<<4)));
      oacc[df] = __builtin_amdgcn_mfma_f32_16x16x32_bf16(pa, vb, oacc[df], 0, 0, 0);
    }
  }
  int orow0 = b*SS + q0 + w*16 + ((l>>4)<<2);
#pragma unroll
  for(int df=0;df<4;df++){
    int col = h*64 + df*16 + (l&15);
#pragma unroll
    for(int j=0;j<4;j++)
      attno[(size_t)(orow0+j)*DD + col] = bfr(oacc[df][j]*rden[j]);
  }
}

// ---------------- gated residual + LN2 fused ----------------
__global__ void k_gateres_ln(const float* __restrict__ z, const float* __restrict__ ao,
                             const float* __restrict__ g, float* __restrict__ x,
                             unsigned short* __restrict__ z2b, const int* __restrict__ dof){
  int tok = blockIdx.x; if(!dof[tok>>8]) return;
  __shared__ float sh[4];
  int tid=threadIdx.x;
  size_t base=(size_t)tok*DD;
  float zz0=z[base+tid],     aa0=ao[base+tid],     gg0=g[base+tid];
  float zz1=z[base+tid+256], aa1=ao[base+tid+256], gg1=g[base+tid+256];
  float t0 = zz0 + aa0/(1.f+expf(-gg0));
  float t1 = zz1 + aa1/(1.f+expf(-gg1));
  float m = block_sum(t0+t1,sh)*(1.f/DD);
  float d0=t0-m, d1=t1-m;
  float var=block_sum(d0*d0+d1*d1,sh)*(1.f/DD);
  float inv=rsqrtf(var+1e-5f);
  float xn0 = x[base+tid]     + d0*inv;
  float xn1 = x[base+tid+256] + d1*inv;
  x[base+tid] = xn0; x[base+tid+256] = xn1;
  float m2 = block_sum(xn0+xn1,sh)*(1.f/DD);
  float e0=xn0-m2, e1=xn1-m2;
  float var2=block_sum(e0*e0+e1*e1,sh)*(1.f/DD);
  float inv2=rsqrtf(var2+1e-5f);
  z2b[base+tid] = bfr(e0*inv2); z2b[base+tid+256] = bfr(e1*inv2);
}

// ---------------- host launcher ----------------
extern "C" void kernel_launch(void* const* d_in, const int* in_sizes, int n_in,
                              void* d_out, int out_size, void* d_ws, size_t ws_size,
                              hipStream_t stream){
  const int*   ids   = (const int*)d_in[0];
  const float* emb   = (const float*)d_in[1];
  const float* r_w1  = (const float*)d_in[2];
  const float* r_b1  = (const float*)d_in[3];
  const float* r_w2  = (const float*)d_in[4];
  const float* r_b2  = (const float*)d_in[5];
  const float* r_q   = (const float*)d_in[6];
  const float* in_w  = (const float*)d_in[7];
  const float* in_b  = (const float*)d_in[8];
  const float* out_w = (const float*)d_in[9];
  const float* out_b = (const float*)d_in[10];
  const float* gate_w= (const float*)d_in[11];
  const float* gate_b= (const float*)d_in[12];
  const float* f_w1  = (const float*)d_in[13];
  const float* f_b1  = (const float*)d_in[14];
  const float* f_w2  = (const float*)d_in[15];
  const float* f_b2  = (const float*)d_in[16];
  const float* tag   = (const float*)d_in[17];
  const float* lm_w  = (const float*)d_in[18];
  const float* lm_b  = (const float*)d_in[19];
  float* out = (float*)d_out;
  float* ws  = (float*)d_ws;

  const size_t M = (size_t)TOK*DD;   // 1,048,576
  float* x      = ws;            // 1M f32
  float* z      = ws + 1*M;      // 1M f32
  float* ao     = ws + 2*M;      // 1M f32
  float* gtmp   = ws + 3*M;      // 1M f32
  int*   ipool  = (int*)(ws + 4*M);
  int* action = ipool; int* dof = ipool+BB; int* active = ipool+2*BB; int* visits = ipool+3*BB;

  unsigned short* ub = (unsigned short*)(ws + 4*M + 64);
  unsigned short* z_bf     = ub;          // 1M
  unsigned short* ao_bf    = ub + 1*M;    // 1M
  unsigned short* z2_bf    = ub + 2*M;    // 1M
  unsigned short* attno_bf = ub + 3*M;    // 1M
  unsigned short* qkv_bf   = ub + 4*M;    // 3M
  unsigned short* ffh_bf   = ub + 7*M;    // 4M
  unsigned short* wb = ub + 11*M;
  unsigned short* in_wb   = wb;
  unsigned short* out_wb  = in_wb  + (size_t)EE*LL*3*DD*DD;
  unsigned short* gate_wb = out_wb + (size_t)EE*LL*DD*DD;
  unsigned short* f_w1b   = gate_wb+ (size_t)EE*LL*DD*2*DD;
  unsigned short* f_w2b   = f_w1b  + (size_t)EE*LL*FFF*DD;
  unsigned short* lm_wb   = f_w2b  + (size_t)EE*LL*DD*FFF;

  k_preproc<<<CASTBLK+TOK,256,0,stream>>>(in_w,out_w,gate_w,f_w1,f_w2,lm_w,
                                          in_wb,out_wb,gate_wb,f_w1b,f_w2b,lm_wb,
                                          ids, emb, x);

  for(int step=0; step<3; step++){
    k_sumrouter<<<BB,256,0,stream>>>(x,r_w1,r_b1,r_w2,r_b2,r_q,action,dof,visits,active,step);
    for(int l=0; l<LL; l++){
      k_ln<<<TOK,256,0,stream>>>(x, z, z_bf, dof);
      k_mgemm<0><<<dim3(BB,2,12),256,0,stream>>>(z_bf,nullptr,DD, in_wb,in_b,1,l, 3*DD,DD, nullptr,qkv_bf, nullptr, action,dof);
      k_attn<<<dim3(BB*NHH,4),256,0,stream>>>(qkv_bf, attno_bf, dof);
      k_mgemm<0><<<dim3(BB,2,4),256,0,stream>>>(attno_bf,nullptr,DD, out_wb,out_b,1,l, DD,DD, ao,ao_bf, nullptr, action,dof);
      k_mgemm<0><<<dim3(BB,2,4),256,0,stream>>>(z_bf,ao_bf,DD, gate_wb,gate_b,1,l, DD,2*DD, gtmp,nullptr, nullptr, action,dof);
      k_gateres_ln<<<TOK,256,0,stream>>>(z,ao,gtmp,x,z2_bf,dof);
      k_mgemm<1><<<dim3(BB,2,16),256,0,stream>>>(z2_bf,nullptr,DD, f_w1b,f_b1,1,l, FFF,DD, nullptr,ffh_bf, nullptr, action,dof);
      k_mgemm<2><<<dim3(BB,2,4),256,0,stream>>>(ffh_bf,nullptr,FFF, f_w2b,f_b2,1,l, DD,FFF, x,nullptr, (l==LL-1)?tag:nullptr, action,dof);
    }
  }

  k_ln<<<TOK,256,0,stream>>>(x, nullptr, z_bf, nullptr);
  k_mgemm<0><<<dim3(1,16,VV/128),256,0,stream>>>(z_bf,nullptr,DD, lm_wb,lm_b,0,0, VV,DD, out,nullptr, nullptr, nullptr,nullptr);
}

// Round 5
// 918.161 us; speedup vs baseline: 3.5974x; 1.1897x over previous
//
#include <hip/hip_runtime.h>
#include <hip/hip_bf16.h>
#include <math.h>

#define BB   8
#define SS   256
#define DD   512
#define NHH  8
#define HDD  64
#define EE   4
#define LL   2
#define FFF  2048
#define RHH  256
#define VV   32000
#define MVV  2
#define TOK  (BB*SS)   // 2048
#define CASTBLK 44672

typedef __attribute__((ext_vector_type(8))) short bf16x8;
typedef __attribute__((ext_vector_type(4))) float f32x4;

// ---------------- helpers ----------------
__device__ __forceinline__ float wred_sum(float v){
#pragma unroll
  for(int o=32;o;o>>=1) v += __shfl_xor(v,o,64);
  return v;
}
__device__ __forceinline__ float block_sum(float v, float* sh){
  v = wred_sum(v);
  if((threadIdx.x&63)==0) sh[threadIdx.x>>6]=v;
  __syncthreads();
  float t = sh[0]+sh[1]+sh[2]+sh[3];
  __syncthreads();
  return t;
}
__device__ __forceinline__ float gelu_exact(float x){
  return 0.5f*x*(1.f+erff(x*0.70710678118654752f));
}
__device__ __forceinline__ unsigned short bfr(float f){
  union{float f; unsigned u;} c; c.f=f;
  unsigned u = c.u;
  return (unsigned short)((u + 0x7FFFu + ((u>>16)&1u)) >> 16);
}

// ---------------- fused: weight casts (blocks < CASTBLK) + embed+PE+LN ----------------
__global__ void k_preproc(const float* __restrict__ s0,const float* __restrict__ s1,
                          const float* __restrict__ s2,const float* __restrict__ s3,
                          const float* __restrict__ s4,const float* __restrict__ s5,
                          unsigned short* __restrict__ d0,unsigned short* __restrict__ d1,
                          unsigned short* __restrict__ d2,unsigned short* __restrict__ d3,
                          unsigned short* __restrict__ d4,unsigned short* __restrict__ d5,
                          const int* __restrict__ ids, const float* __restrict__ emb,
                          float* __restrict__ x){
  __shared__ float sh[4];
  if(blockIdx.x < CASTBLK){
    long i = (long)blockIdx.x*256 + threadIdx.x;
    const float* s; unsigned short* d; long o;
    if(i < 1572864L){ s=s0; d=d0; o=i; }
    else if(i < 2097152L){ s=s1; d=d1; o=i-1572864L; }
    else if(i < 3145728L){ s=s2; d=d2; o=i-2097152L; }
    else if(i < 5242880L){ s=s3; d=d3; o=i-3145728L; }
    else if(i < 7340032L){ s=s4; d=d4; o=i-5242880L; }
    else { s=s5; d=d5; o=i-7340032L; }
    float4 v = ((const float4*)s)[o];
    ushort4 u; u.x=bfr(v.x); u.y=bfr(v.y); u.z=bfr(v.z); u.w=bfr(v.w);
    ((ushort4*)d)[o] = u;
    return;
  }
  int tok = blockIdx.x - CASTBLK;
  int s = tok & (SS-1);
  int tid = threadIdx.x;
  int id = ids[tok];
  float v[2];
#pragma unroll
  for(int i=0;i<2;i++){
    int d = tid + i*256;
    float e = emb[(size_t)id*DD + d] * 22.627416997969522f; // sqrt(512)
    int j = d >> 1;
    float freq = expf((float)(2*j) * (-0.0179889460390160f)); // -ln(1e4)/512
    float arg = (float)s * freq;
    v[i] = e + ((d & 1) ? cosf(arg) : sinf(arg));
  }
  float m = block_sum(v[0]+v[1], sh) * (1.f/DD);
  float dd0=v[0]-m, dd1=v[1]-m;
  float var = block_sum(dd0*dd0+dd1*dd1, sh) * (1.f/DD);
  float inv = rsqrtf(var + 1e-5f);
  float* q = x + (size_t)tok*DD;
  q[tid] = dd0*inv; q[tid+256] = dd1*inv;
}

// ---------------- LN ----------------
__global__ void k_ln(const float* __restrict__ in, float* __restrict__ outf,
                     unsigned short* __restrict__ outb, const int* __restrict__ dof){
  int tok = blockIdx.x;
  if(dof && !dof[tok>>8]) return;
  __shared__ float sh[4];
  int tid = threadIdx.x;
  const float* p = in + (size_t)tok*DD;
  float a0 = p[tid], a1 = p[tid+256];
  float m = block_sum(a0+a1, sh) * (1.f/DD);
  float d0=a0-m, d1=a1-m;
  float var = block_sum(d0*d0+d1*d1, sh) * (1.f/DD);
  float inv = rsqrtf(var + 1e-5f);
  float r0 = d0*inv, r1 = d1*inv;
  if(outf){ float* q = outf + (size_t)tok*DD; q[tid] = r0; q[tid+256] = r1; }
  if(outb){ unsigned short* q = outb + (size_t)tok*DD; q[tid] = bfr(r0); q[tid+256] = bfr(r1); }
}

// ---------------- partial summary: psum[b][p][d] = sum over 16 tokens ----------------
__global__ void k_psum(const float* __restrict__ x, float* __restrict__ psum){
  int b = blockIdx.x, p = blockIdx.y;
  int tid = threadIdx.x;
  const float* xb = x + (size_t)(b*SS + p*16)*DD;
  float s0=0.f, s1=0.f;
  for(int tt=0; tt<16; tt++){
    s0 += xb[(size_t)tt*DD + tid];
    s1 += xb[(size_t)tt*DD + tid + 256];
  }
  float* q = psum + (size_t)(b*16+p)*DD;
  q[tid] = s0; q[tid+256] = s1;
}

// ---------------- router (reduces psum partials) ----------------
__global__ void k_router(const float* __restrict__ psum,
                         const float* __restrict__ r_w1, const float* __restrict__ r_b1,
                         const float* __restrict__ r_w2, const float* __restrict__ r_b2,
                         const float* __restrict__ r_q,
                         int* __restrict__ action, int* __restrict__ dof,
                         int* __restrict__ visits, int* __restrict__ active, int step){
  int b = blockIdx.x; int tid = threadIdx.x;
  if(step==0 && tid==0){ active[b]=1; for(int e=0;e<EE;e++) visits[b*EE+e]=0; }
  __shared__ float ssum[DD];
  __shared__ float hid[RHH];
  __shared__ float lg[EE+1];
  float s0=0.f, s1=0.f;
  for(int p=0;p<16;p++){
    const float* q = psum + (size_t)(b*16+p)*DD;
    s0 += q[tid]; s1 += q[tid+256];
  }
  ssum[tid] = s0*(1.f/SS); ssum[tid+256] = s1*(1.f/SS);
  __syncthreads();
  float acc = r_b1[tid];
  const float4* wr4 = (const float4*)(r_w1 + (size_t)tid*DD);
  for(int d4=0; d4<DD/4; d4++){
    float4 wv = wr4[d4];
    float4 sv = *(const float4*)&ssum[d4*4];
    acc += wv.x*sv.x + wv.y*sv.y + wv.z*sv.z + wv.w*sv.w;
  }
  hid[tid] = gelu_exact(acc);
  __syncthreads();
  if(tid < EE+1){
    const float* w2 = r_w2 + (size_t)tid*RHH;
    float a = r_b2[tid] + r_q[tid];
    for(int j=0;j<RHH;j++) a += hid[j]*w2[j];
    lg[tid]=a;
  }
  __syncthreads();
  if(tid==0){
    float m=0.f; for(int k=0;k<EE+1;k++) m+=lg[k]; m *= (1.f/(EE+1));
    float v=0.f; for(int k=0;k<EE+1;k++){float d=lg[k]-m; v+=d*d;} v *= (1.f/(EE+1));
    float inv = rsqrtf(v+1e-5f);
    float best=-1e38f; int bi=0;
    for(int k=0;k<EE+1;k++){
      float fl = (lg[k]-m)*inv;
      fl = fminf(fmaxf(fl,-10.f),10.f);
      if(k<EE && visits[b*EE+k]>=MVV) fl = -1e38f;
      if(fl > best){best=fl; bi=k;}
    }
    int dd = (active[b] && bi<EE) ? 1 : 0;
    action[b]=bi; dof[b]=dd;
    if(dd) visits[b*EE+bi]++;
    active[b]=dd;
  }
}

// ---------------- bf16 MFMA GEMM, TMx128 tile, BK=64, 2-phase double-buffered ----------------
// TM=128: 4 waves 2x2, each 64x64 (acc 4x4).  TM=64: 4 waves 1x4, each 64x32 (acc 4x2).
// EPI: 0 = store (Cf and/or Cb), 1 = gelu -> Cb, 2 = Cf += (+ tag if tagp)
template<int EPI, int TM>
__global__ __launch_bounds__(256)
void k_mgemm(const unsigned short* __restrict__ A1, const unsigned short* __restrict__ A2,
             int ksplit,
             const unsigned short* __restrict__ Wb, const float* __restrict__ bb,
             int wsel, int l, int N, int K,
             float* __restrict__ Cf, unsigned short* __restrict__ Cb,
             const float* __restrict__ tagp,
             const int* __restrict__ action, const int* __restrict__ dof){
  constexpr int NN    = (TM==128) ? 4 : 2;   // col frags per wave
  constexpr int ISS_A = TM/32;               // A stage issues per thread
  int b = blockIdx.x;
  if(dof && !dof[b]) return;
  const unsigned short* W = Wb; const float* bias = bb;
  if(wsel){ size_t o = (size_t)(action[b]*LL + l); W += o*(size_t)N*K; bias += o*N; }
  int rowbase = b*SS + blockIdx.y*TM;
  int colbase = blockIdx.z*128;
  __shared__ unsigned short sA[2*TM*64];
  __shared__ unsigned short sW[2*128*64];
  int t = threadIdx.x;
  int lane = t & 63;
  int w = t >> 6;
  int wrow0, wcol0;
  if constexpr(TM==128){ wrow0 = (w>>1)*64; wcol0 = (w&1)*64; }
  else                 { wrow0 = 0;         wcol0 = w*32; }
  int sr = t >> 3;          // 0..31
  int ss8 = t & 7;          // 16B slot

  f32x4 acc[4][NN];
#pragma unroll
  for(int m=0;m<4;m++)
#pragma unroll
    for(int n=0;n<NN;n++) acc[m][n] = (f32x4){0.f,0.f,0.f,0.f};

  auto STAGE = [&](int buf, int k0){
    const unsigned short* Ab; int kb0, kstr;
    if(k0 < ksplit){ Ab = A1; kb0 = k0;          kstr = ksplit; }
    else           { Ab = A2; kb0 = k0 - ksplit; kstr = K - ksplit; }
    unsigned short* dA = sA + buf*(TM*64);
    unsigned short* dW = sW + buf*8192;
#pragma unroll
    for(int i = 0; i < ISS_A; i++){
      int r  = i*32 + sr;
      int ce = ((ss8<<4) ^ ((r&7)<<4)) >> 1;
      const unsigned short* gp = Ab + (size_t)(rowbase + r)*kstr + kb0 + ce;
      __builtin_amdgcn_global_load_lds((const __attribute__((address_space(1))) void*)gp,
          (__attribute__((address_space(3))) void*)(dA + i*2048 + t*8), 16, 0, 0);
    }
#pragma unroll
    for(int i = 0; i < 4; i++){
      int r  = i*32 + sr;
      int ce = ((ss8<<4) ^ ((r&7)<<4)) >> 1;
      const unsigned short* gw = W + (size_t)(colbase + r)*K + k0 + ce;
      __builtin_amdgcn_global_load_lds((const __attribute__((address_space(1))) void*)gw,
          (__attribute__((address_space(3))) void*)(dW + i*2048 + t*8), 16, 0, 0);
    }
  };

  STAGE(0, 0);
  int cur = 0;
  for(int k0 = 0; k0 < K; k0 += 64){
    if(k0 + 64 < K){
      STAGE(cur^1, k0+64);                               // prefetch next tile
      if constexpr(TM==128) asm volatile("s_waitcnt vmcnt(8)" ::: "memory");
      else                  asm volatile("s_waitcnt vmcnt(6)" ::: "memory");
    } else {
      asm volatile("s_waitcnt vmcnt(0)" ::: "memory");
    }
    __builtin_amdgcn_s_barrier();
    __builtin_amdgcn_sched_barrier(0);
    const char* bA = (const char*)(sA + cur*(TM*64));
    const char* bW = (const char*)(sW + cur*8192);
#pragma unroll
    for(int ks = 0; ks < 2; ks++){
      bf16x8 af[4], wf[NN];
#pragma unroll
      for(int m = 0; m < 4; m++){
        int r = wrow0 + m*16 + (lane & 15);
        af[m] = *(const bf16x8*)(bA + r*128 + (((((lane>>4)<<4)|(ks<<6))) ^ ((r&7)<<4)));
      }
#pragma unroll
      for(int n = 0; n < NN; n++){
        int r = wcol0 + n*16 + (lane & 15);
        wf[n] = *(const bf16x8*)(bW + r*128 + (((((lane>>4)<<4)|(ks<<6))) ^ ((r&7)<<4)));
      }
#pragma unroll
      for(int m = 0; m < 4; m++)
#pragma unroll
        for(int n = 0; n < NN; n++)
          acc[m][n] = __builtin_amdgcn_mfma_f32_16x16x32_bf16(af[m], wf[n], acc[m][n], 0, 0, 0);
    }
    asm volatile("s_waitcnt lgkmcnt(0)" ::: "memory");
    __builtin_amdgcn_s_barrier();
    cur ^= 1;
  }
  int orow0 = rowbase + wrow0 + ((lane >> 4) << 2);
  int ocol0 = colbase + wcol0 + (lane & 15);
#pragma unroll
  for(int m = 0; m < 4; m++){
#pragma unroll
    for(int n = 0; n < NN; n++){
      int col = ocol0 + n*16;
      float bv = bias[col];
      float tg = 0.f;
      if(EPI == 2 && tagp) tg = tagp[(size_t)action[b]*DD + col];
#pragma unroll
      for(int j = 0; j < 4; j++){
        int row = orow0 + m*16 + j;
        size_t idx = (size_t)row*N + col;
        float v = acc[m][n][j] + bv;
        if(EPI == 0){ if(Cf) Cf[idx] = v; if(Cb) Cb[idx] = bfr(v); }
        else if(EPI == 1){ Cb[idx] = bfr(gelu_exact(v)); }
        else { Cf[idx] += v + tg; }
      }
    }
  }
}

// ---------------- fused attention: softmax(QK^T/8) @ V, bf16 MFMA ----------------
__global__ __launch_bounds__(256)
void k_attn(const unsigned short* __restrict__ qkv, unsigned short* __restrict__ attno,
            const int* __restrict__ dof){
  int bh = blockIdx.x; int b = bh>>3, h = bh&7;
  if(!dof[b]) return;
  int q0 = blockIdx.y*64;
  __shared__ unsigned short sK[256*64];   // 32KB; reused as P after scores
  __shared__ unsigned short sVT[64*256];  // 32KB, V transposed [d][k]
  int t = threadIdx.x, l = t&63, w = t>>6;
  const unsigned short* qbase = qkv + (size_t)b*SS*1536;

  {
    int sr = t>>3, s8 = t&7;
#pragma unroll
    for(int i=0;i<8;i++){
      int r = i*32 + sr;
      int ce = ((s8<<4) ^ ((r&7)<<4)) >> 1;
      const unsigned short* gp = qbase + (size_t)r*1536 + 512 + h*64 + ce;
      __builtin_amdgcn_global_load_lds((const __attribute__((address_space(1))) void*)gp,
          (__attribute__((address_space(3))) void*)(sK + i*2048 + t*8), 16, 0, 0);
    }
  }
  {
    int kt0 = t>>2, dg = (t&3)*16;
#pragma unroll
    for(int i=0;i<4;i++){
      int kt = i*64 + kt0;
      const unsigned short* gp = qbase + (size_t)kt*1536 + 1024 + h*64 + dg;
      bf16x8 v0 = *(const bf16x8*)gp;
      bf16x8 v1 = *(const bf16x8*)(gp+8);
#pragma unroll
      for(int e=0;e<8;e++){
        int d  = dg+e;
        *(unsigned short*)((char*)sVT + d*512  + ((kt*2) ^ ((d&7)<<4)))  = (unsigned short)v0[e];
        int d2 = dg+8+e;
        *(unsigned short*)((char*)sVT + d2*512 + ((kt*2) ^ ((d2&7)<<4))) = (unsigned short)v1[e];
      }
    }
  }
  bf16x8 qf[2];
  {
    const unsigned short* qrow = qbase + (size_t)(q0 + w*16 + (l&15))*1536 + h*64;
    qf[0] = *(const bf16x8*)(qrow + ((l>>4)<<3));
    qf[1] = *(const bf16x8*)(qrow + ((l>>4)<<3) + 32);
  }
  __syncthreads();

  f32x4 sacc[16];
#pragma unroll
  for(int kb=0;kb<16;kb++) sacc[kb] = (f32x4){0.f,0.f,0.f,0.f};
#pragma unroll
  for(int kb=0;kb<16;kb++){
    int rk = kb*16 + (l&15);
#pragma unroll
    for(int ks=0;ks<2;ks++){
      bf16x8 kf = *(const bf16x8*)((const char*)sK + rk*128 + (((((l>>4)<<4)|(ks<<6))) ^ ((rk&7)<<4)));
      sacc[kb] = __builtin_amdgcn_mfma_f32_16x16x32_bf16(qf[ks], kf, sacc[kb], 0, 0, 0);
    }
  }
  float rden[4];
#pragma unroll
  for(int j=0;j<4;j++){
    float m = -1e38f;
#pragma unroll
    for(int kb=0;kb<16;kb++) m = fmaxf(m, sacc[kb][j]);
#pragma unroll
    for(int o=1;o<16;o<<=1) m = fmaxf(m, __shfl_xor(m,o,64));
    m *= 0.125f;
    float s = 0.f;
#pragma unroll
    for(int kb=0;kb<16;kb++){
      float e = expf(sacc[kb][j]*0.125f - m);
      sacc[kb][j] = e; s += e;
    }
#pragma unroll
    for(int o=1;o<16;o<<=1) s += __shfl_xor(s,o,64);
    rden[j] = 1.f/s;
  }
  __syncthreads();

  char* sP = (char*)sK + w*8192;
#pragma unroll
  for(int kb=0;kb<16;kb++){
    int k = kb*16 + (l&15);
#pragma unroll
    for(int j=0;j<4;j++){
      int qr = ((l>>4)<<2) + j;
      *(unsigned short*)(sP + qr*512 + ((k*2) ^ ((qr&7)<<4))) = bfr(sacc[kb][j]);
    }
  }
  __syncthreads();

  f32x4 oacc[4];
#pragma unroll
  for(int df=0;df<4;df++) oacc[df] = (f32x4){0.f,0.f,0.f,0.f};
#pragma unroll
  for(int kstep=0;kstep<8;kstep++){
    bf16x8 pa = *(const bf16x8*)(sP + (l&15)*512 + ((((kstep<<6)|((l>>4)<<4))) ^ ((l&7)<<4)));
#pragma unroll
    for(int df=0;df<4;df++){
      int d = df*16 + (l&15);
      bf16x8 vb = *(const bf16x8*)((char*)sVT + d*512 + ((((kstep<<6)|((l>>4)<<4))) ^ ((d&7)<<4)));
      oacc[df] = __builtin_amdgcn_mfma_f32_16x16x32_bf16(pa, vb, oacc[df], 0, 0, 0);
    }
  }
  int orow0 = b*SS + q0 + w*16 + ((l>>4)<<2);
#pragma unroll
  for(int df=0;df<4;df++){
    int col = h*64 + df*16 + (l&15);
#pragma unroll
    for(int j=0;j<4;j++)
      attno[(size_t)(orow0+j)*DD + col] = bfr(oacc[df][j]*rden[j]);
  }
}

// ---------------- gated residual + LN2 fused ----------------
__global__ void k_gateres_ln(const float* __restrict__ z, const float* __restrict__ ao,
                             const float* __restrict__ g, float* __restrict__ x,
                             unsigned short* __restrict__ z2b, const int* __restrict__ dof){
  int tok = blockIdx.x; if(!dof[tok>>8]) return;
  __shared__ float sh[4];
  int tid=threadIdx.x;
  size_t base=(size_t)tok*DD;
  float zz0=z[base+tid],     aa0=ao[base+tid],     gg0=g[base+tid];
  float zz1=z[base+tid+256], aa1=ao[base+tid+256], gg1=g[base+tid+256];
  float t0 = zz0 + aa0/(1.f+expf(-gg0));
  float t1 = zz1 + aa1/(1.f+expf(-gg1));
  float m = block_sum(t0+t1,sh)*(1.f/DD);
  float d0=t0-m, d1=t1-m;
  float var=block_sum(d0*d0+d1*d1,sh)*(1.f/DD);
  float inv=rsqrtf(var+1e-5f);
  float xn0 = x[base+tid]     + d0*inv;
  float xn1 = x[base+tid+256] + d1*inv;
  x[base+tid] = xn0; x[base+tid+256] = xn1;
  float m2 = block_sum(xn0+xn1,sh)*(1.f/DD);
  float e0=xn0-m2, e1=xn1-m2;
  float var2=block_sum(e0*e0+e1*e1,sh)*(1.f/DD);
  float inv2=rsqrtf(var2+1e-5f);
  z2b[base+tid] = bfr(e0*inv2); z2b[base+tid+256] = bfr(e1*inv2);
}

// ---------------- host launcher ----------------
extern "C" void kernel_launch(void* const* d_in, const int* in_sizes, int n_in,
                              void* d_out, int out_size, void* d_ws, size_t ws_size,
                              hipStream_t stream){
  const int*   ids   = (const int*)d_in[0];
  const float* emb   = (const float*)d_in[1];
  const float* r_w1  = (const float*)d_in[2];
  const float* r_b1  = (const float*)d_in[3];
  const float* r_w2  = (const float*)d_in[4];
  const float* r_b2  = (const float*)d_in[5];
  const float* r_q   = (const float*)d_in[6];
  const float* in_w  = (const float*)d_in[7];
  const float* in_b  = (const float*)d_in[8];
  const float* out_w = (const float*)d_in[9];
  const float* out_b = (const float*)d_in[10];
  const float* gate_w= (const float*)d_in[11];
  const float* gate_b= (const float*)d_in[12];
  const float* f_w1  = (const float*)d_in[13];
  const float* f_b1  = (const float*)d_in[14];
  const float* f_w2  = (const float*)d_in[15];
  const float* f_b2  = (const float*)d_in[16];
  const float* tag   = (const float*)d_in[17];
  const float* lm_w  = (const float*)d_in[18];
  const float* lm_b  = (const float*)d_in[19];
  float* out = (float*)d_out;
  float* ws  = (float*)d_ws;

  const size_t M = (size_t)TOK*DD;   // 1,048,576
  float* x      = ws;            // 1M f32
  float* z      = ws + 1*M;      // 1M f32
  float* ao     = ws + 2*M;      // 1M f32
  float* gtmp   = ws + 3*M;      // 1M f32
  int*   ipool  = (int*)(ws + 4*M);
  int* action = ipool; int* dof = ipool+BB; int* active = ipool+2*BB; int* visits = ipool+3*BB;
  float* psum   = ws + 4*M + 64;       // [8][16][512] = 65536 f32

  unsigned short* ub = (unsigned short*)(ws + 4*M + 64 + 65536);
  unsigned short* z_bf     = ub;          // 1M
  unsigned short* ao_bf    = ub + 1*M;    // 1M
  unsigned short* z2_bf    = ub + 2*M;    // 1M
  unsigned short* attno_bf = ub + 3*M;    // 1M
  unsigned short* qkv_bf   = ub + 4*M;    // 3M
  unsigned short* ffh_bf   = ub + 7*M;    // 4M
  unsigned short* wb = ub + 11*M;
  unsigned short* in_wb   = wb;
  unsigned short* out_wb  = in_wb  + (size_t)EE*LL*3*DD*DD;
  unsigned short* gate_wb = out_wb + (size_t)EE*LL*DD*DD;
  unsigned short* f_w1b   = gate_wb+ (size_t)EE*LL*DD*2*DD;
  unsigned short* f_w2b   = f_w1b  + (size_t)EE*LL*FFF*DD;
  unsigned short* lm_wb   = f_w2b  + (size_t)EE*LL*DD*FFF;

  k_preproc<<<CASTBLK+TOK,256,0,stream>>>(in_w,out_w,gate_w,f_w1,f_w2,lm_w,
                                          in_wb,out_wb,gate_wb,f_w1b,f_w2b,lm_wb,
                                          ids, emb, x);

  for(int step=0; step<3; step++){
    k_psum<<<dim3(BB,16),256,0,stream>>>(x, psum);
    k_router<<<BB,256,0,stream>>>(psum,r_w1,r_b1,r_w2,r_b2,r_q,action,dof,visits,active,step);
    for(int l=0; l<LL; l++){
      k_ln<<<TOK,256,0,stream>>>(x, z, z_bf, dof);
      k_mgemm<0,64><<<dim3(BB,4,12),256,0,stream>>>(z_bf,nullptr,DD, in_wb,in_b,1,l, 3*DD,DD, nullptr,qkv_bf, nullptr, action,dof);
      k_attn<<<dim3(BB*NHH,4),256,0,stream>>>(qkv_bf, attno_bf, dof);
      k_mgemm<0,64><<<dim3(BB,4,4),256,0,stream>>>(attno_bf,nullptr,DD, out_wb,out_b,1,l, DD,DD, ao,ao_bf, nullptr, action,dof);
      k_mgemm<0,64><<<dim3(BB,4,4),256,0,stream>>>(z_bf,ao_bf,DD, gate_wb,gate_b,1,l, DD,2*DD, gtmp,nullptr, nullptr, action,dof);
      k_gateres_ln<<<TOK,256,0,stream>>>(z,ao,gtmp,x,z2_bf,dof);
      k_mgemm<1,64><<<dim3(BB,4,16),256,0,stream>>>(z2_bf,nullptr,DD, f_w1b,f_b1,1,l, FFF,DD, nullptr,ffh_bf, nullptr, action,dof);
      k_mgemm<2,64><<<dim3(BB,4,4),256,0,stream>>>(ffh_bf,nullptr,FFF, f_w2b,f_b2,1,l, DD,FFF, x,nullptr, (l==LL-1)?tag:nullptr, action,dof);
    }
  }

  k_ln<<<TOK,256,0,stream>>>(x, nullptr, z_bf, nullptr);
  k_mgemm<0,128><<<dim3(1,16,VV/128),256,0,stream>>>(z_bf,nullptr,DD, lm_wb,lm_b,0,0, VV,DD, out,nullptr, nullptr, nullptr,nullptr);
}

// Round 6
// 750.712 us; speedup vs baseline: 4.3999x; 1.2231x over previous
//
#include <hip/hip_runtime.h>
#include <hip/hip_bf16.h>
#include <math.h>

#define BB   8
#define SS   256
#define DD   512
#define NHH  8
#define HDD  64
#define EE   4
#define LL   2
#define FFF  2048
#define RHH  256
#define VV   32000
#define MVV  2
#define TOK  (BB*SS)   // 2048
#define CASTBLK 44672

typedef __attribute__((ext_vector_type(8))) short bf16x8;
typedef __attribute__((ext_vector_type(4))) float f32x4;

// ---------------- helpers ----------------
__device__ __forceinline__ float wred_sum(float v){
#pragma unroll
  for(int o=32;o;o>>=1) v += __shfl_xor(v,o,64);
  return v;
}
__device__ __forceinline__ float block_sum(float v, float* sh){
  v = wred_sum(v);
  if((threadIdx.x&63)==0) sh[threadIdx.x>>6]=v;
  __syncthreads();
  float t = sh[0]+sh[1]+sh[2]+sh[3];
  __syncthreads();
  return t;
}
__device__ __forceinline__ float gelu_exact(float x){
  return 0.5f*x*(1.f+erff(x*0.70710678118654752f));
}
__device__ __forceinline__ unsigned short bfr(float f){
  union{float f; unsigned u;} c; c.f=f;
  unsigned u = c.u;
  return (unsigned short)((u + 0x7FFFu + ((u>>16)&1u)) >> 16);
}

// ---------------- fused: weight casts + embed+PE+LN ----------------
__global__ void k_preproc(const float* __restrict__ s0,const float* __restrict__ s1,
                          const float* __restrict__ s2,const float* __restrict__ s3,
                          const float* __restrict__ s4,const float* __restrict__ s5,
                          unsigned short* __restrict__ d0,unsigned short* __restrict__ d1,
                          unsigned short* __restrict__ d2,unsigned short* __restrict__ d3,
                          unsigned short* __restrict__ d4,unsigned short* __restrict__ d5,
                          const int* __restrict__ ids, const float* __restrict__ emb,
                          float* __restrict__ x){
  __shared__ float sh[4];
  if(blockIdx.x < CASTBLK){
    long i = (long)blockIdx.x*256 + threadIdx.x;
    const float* s; unsigned short* d; long o;
    if(i < 1572864L){ s=s0; d=d0; o=i; }
    else if(i < 2097152L){ s=s1; d=d1; o=i-1572864L; }
    else if(i < 3145728L){ s=s2; d=d2; o=i-2097152L; }
    else if(i < 5242880L){ s=s3; d=d3; o=i-3145728L; }
    else if(i < 7340032L){ s=s4; d=d4; o=i-5242880L; }
    else { s=s5; d=d5; o=i-7340032L; }
    float4 v = ((const float4*)s)[o];
    ushort4 u; u.x=bfr(v.x); u.y=bfr(v.y); u.z=bfr(v.z); u.w=bfr(v.w);
    ((ushort4*)d)[o] = u;
    return;
  }
  int tok = blockIdx.x - CASTBLK;
  int s = tok & (SS-1);
  int tid = threadIdx.x;
  int id = ids[tok];
  float v[2];
#pragma unroll
  for(int i=0;i<2;i++){
    int d = tid + i*256;
    float e = emb[(size_t)id*DD + d] * 22.627416997969522f; // sqrt(512)
    int j = d >> 1;
    float freq = expf((float)(2*j) * (-0.0179889460390160f)); // -ln(1e4)/512
    float arg = (float)s * freq;
    v[i] = e + ((d & 1) ? cosf(arg) : sinf(arg));
  }
  float m = block_sum(v[0]+v[1], sh) * (1.f/DD);
  float dd0=v[0]-m, dd1=v[1]-m;
  float var = block_sum(dd0*dd0+dd1*dd1, sh) * (1.f/DD);
  float inv = rsqrtf(var + 1e-5f);
  float* q = x + (size_t)tok*DD;
  q[tid] = dd0*inv; q[tid+256] = dd1*inv;
}

// ---------------- combine(+x ping-pong) + LN + optional psum ----------------
// tok blocks: v = xin (+ P0+P1 if dof); if(P0) xout=v; z,z_bf = LN(v)
// psum blocks (grid > TOK): partial sums of v (read-only recompute)
__global__ void k_lnpsum(const float* __restrict__ xin, const float* __restrict__ P0,
                         const float* __restrict__ P1, float* __restrict__ xout,
                         float* __restrict__ zf, unsigned short* __restrict__ zb,
                         float* __restrict__ psum, const int* __restrict__ dof){
  __shared__ float sh[4];
  int tid = threadIdx.x;
  if(blockIdx.x < TOK){
    int tok = blockIdx.x; int b = tok>>8;
    size_t base = (size_t)tok*DD;
    float a0 = xin[base+tid], a1 = xin[base+tid+256];
    if(P0){
      if(dof[b]){
        a0 += P0[base+tid]     + P1[base+tid];
        a1 += P0[base+tid+256] + P1[base+tid+256];
      }
      xout[base+tid] = a0; xout[base+tid+256] = a1;
    }
    float m = block_sum(a0+a1, sh) * (1.f/DD);
    float d0=a0-m, d1=a1-m;
    float var = block_sum(d0*d0+d1*d1, sh) * (1.f/DD);
    float inv = rsqrtf(var + 1e-5f);
    zf[base+tid] = d0*inv; zf[base+tid+256] = d1*inv;
    zb[base+tid] = bfr(d0*inv); zb[base+tid+256] = bfr(d1*inv);
  } else {
    int pb = blockIdx.x - TOK; int b = pb>>4, p = pb&15;
    bool c = (P0 != nullptr) && dof[b];
    float s0=0.f, s1=0.f;
    for(int tt=0; tt<16; tt++){
      size_t r = (size_t)(b*SS + p*16 + tt)*DD;
      float v0 = xin[r+tid], v1 = xin[r+tid+256];
      if(c){ v0 += P0[r+tid]+P1[r+tid]; v1 += P0[r+tid+256]+P1[r+tid+256]; }
      s0 += v0; s1 += v1;
    }
    float* q = psum + (size_t)(b*16+p)*DD;
    q[tid] = s0; q[tid+256] = s1;
  }
}

// ---------------- router (reduces psum partials) ----------------
__global__ void k_router(const float* __restrict__ psum,
                         const float* __restrict__ r_w1, const float* __restrict__ r_b1,
                         const float* __restrict__ r_w2, const float* __restrict__ r_b2,
                         const float* __restrict__ r_q,
                         int* __restrict__ action, int* __restrict__ dof,
                         int* __restrict__ visits, int* __restrict__ active, int step){
  int b = blockIdx.x; int tid = threadIdx.x;
  if(step==0 && tid==0){ active[b]=1; for(int e=0;e<EE;e++) visits[b*EE+e]=0; }
  __shared__ float ssum[DD];
  __shared__ float hid[RHH];
  __shared__ float lg[EE+1];
  float s0=0.f, s1=0.f;
  for(int p=0;p<16;p++){
    const float* q = psum + (size_t)(b*16+p)*DD;
    s0 += q[tid]; s1 += q[tid+256];
  }
  ssum[tid] = s0*(1.f/SS); ssum[tid+256] = s1*(1.f/SS);
  __syncthreads();
  float acc = r_b1[tid];
  const float4* wr4 = (const float4*)(r_w1 + (size_t)tid*DD);
  for(int d4=0; d4<DD/4; d4++){
    float4 wv = wr4[d4];
    float4 sv = *(const float4*)&ssum[d4*4];
    acc += wv.x*sv.x + wv.y*sv.y + wv.z*sv.z + wv.w*sv.w;
  }
  hid[tid] = gelu_exact(acc);
  __syncthreads();
  if(tid < EE+1){
    const float* w2 = r_w2 + (size_t)tid*RHH;
    float a = r_b2[tid] + r_q[tid];
    for(int j=0;j<RHH;j++) a += hid[j]*w2[j];
    lg[tid]=a;
  }
  __syncthreads();
  if(tid==0){
    float m=0.f; for(int k=0;k<EE+1;k++) m+=lg[k]; m *= (1.f/(EE+1));
    float v=0.f; for(int k=0;k<EE+1;k++){float d=lg[k]-m; v+=d*d;} v *= (1.f/(EE+1));
    float inv = rsqrtf(v+1e-5f);
    float best=-1e38f; int bi=0;
    for(int k=0;k<EE+1;k++){
      float fl = (lg[k]-m)*inv;
      fl = fminf(fmaxf(fl,-10.f),10.f);
      if(k<EE && visits[b*EE+k]>=MVV) fl = -1e38f;
      if(fl > best){best=fl; bi=k;}
    }
    int dd = (active[b] && bi<EE) ? 1 : 0;
    action[b]=bi; dof[b]=dd;
    if(dd) visits[b*EE+bi]++;
    active[b]=dd;
  }
}

// ---------------- generic 64x128 MFMA GEMM core, BK=64, 2-phase dbuf ----------------
// EPI: 0 = store (Cf and/or Cb), 1 = gelu -> Cb, 2 = Cf += v
template<int EPI>
__device__ __forceinline__ void mg64(
    unsigned short* sA, unsigned short* sW,
    const unsigned short* __restrict__ A, int Ald,
    const unsigned short* __restrict__ W, int Wld,
    const float* __restrict__ bias, const float* __restrict__ tagv,
    int N, int K,
    float* __restrict__ Cf, unsigned short* __restrict__ Cb,
    int rowbase, int colbase){
  int t = threadIdx.x;
  int lane = t & 63;
  int w = t >> 6;
  int wcol0 = w*32;
  int sr = t >> 3, ss8 = t & 7;

  f32x4 acc[4][2];
#pragma unroll
  for(int m=0;m<4;m++)
#pragma unroll
    for(int n=0;n<2;n++) acc[m][n] = (f32x4){0.f,0.f,0.f,0.f};

  auto STAGE = [&](int buf, int k0){
    unsigned short* dA = sA + buf*4096;
    unsigned short* dW = sW + buf*8192;
#pragma unroll
    for(int i = 0; i < 2; i++){
      int r  = i*32 + sr;
      int ce = ((ss8<<4) ^ ((r&7)<<4)) >> 1;
      const unsigned short* gp = A + (size_t)(rowbase + r)*Ald + k0 + ce;
      __builtin_amdgcn_global_load_lds((const __attribute__((address_space(1))) void*)gp,
          (__attribute__((address_space(3))) void*)(dA + i*2048 + t*8), 16, 0, 0);
    }
#pragma unroll
    for(int i = 0; i < 4; i++){
      int r  = i*32 + sr;
      int ce = ((ss8<<4) ^ ((r&7)<<4)) >> 1;
      const unsigned short* gw = W + (size_t)(colbase + r)*Wld + k0 + ce;
      __builtin_amdgcn_global_load_lds((const __attribute__((address_space(1))) void*)gw,
          (__attribute__((address_space(3))) void*)(dW + i*2048 + t*8), 16, 0, 0);
    }
  };

  STAGE(0, 0);
  int cur = 0;
  for(int k0 = 0; k0 < K; k0 += 64){
    if(k0 + 64 < K){
      STAGE(cur^1, k0+64);
      asm volatile("s_waitcnt vmcnt(6)" ::: "memory");
    } else {
      asm volatile("s_waitcnt vmcnt(0)" ::: "memory");
    }
    __builtin_amdgcn_s_barrier();
    __builtin_amdgcn_sched_barrier(0);
    const char* bA = (const char*)(sA + cur*4096);
    const char* bW = (const char*)(sW + cur*8192);
#pragma unroll
    for(int ks = 0; ks < 2; ks++){
      bf16x8 af[4], wf[2];
#pragma unroll
      for(int m = 0; m < 4; m++){
        int r = m*16 + (lane & 15);
        af[m] = *(const bf16x8*)(bA + r*128 + (((((lane>>4)<<4)|(ks<<6))) ^ ((r&7)<<4)));
      }
#pragma unroll
      for(int n = 0; n < 2; n++){
        int r = wcol0 + n*16 + (lane & 15);
        wf[n] = *(const bf16x8*)(bW + r*128 + (((((lane>>4)<<4)|(ks<<6))) ^ ((r&7)<<4)));
      }
#pragma unroll
      for(int m = 0; m < 4; m++)
#pragma unroll
        for(int n = 0; n < 2; n++)
          acc[m][n] = __builtin_amdgcn_mfma_f32_16x16x32_bf16(af[m], wf[n], acc[m][n], 0, 0, 0);
    }
    asm volatile("s_waitcnt lgkmcnt(0)" ::: "memory");
    __builtin_amdgcn_s_barrier();
    cur ^= 1;
  }
  int orow0 = rowbase + ((lane >> 4) << 2);
  int ocol0 = colbase + wcol0 + (lane & 15);
#pragma unroll
  for(int m = 0; m < 4; m++){
#pragma unroll
    for(int n = 0; n < 2; n++){
      int col = ocol0 + n*16;
      float addv = (bias ? bias[col] : 0.f) + (tagv ? tagv[col] : 0.f);
#pragma unroll
      for(int j = 0; j < 4; j++){
        int row = orow0 + m*16 + j;
        size_t idx = (size_t)row*N + col;
        float v = acc[m][n][j] + addv;
        if(EPI == 0){ if(Cf) Cf[idx] = v; if(Cb) Cb[idx] = bfr(v); }
        else if(EPI == 1){ Cb[idx] = bfr(gelu_exact(v)); }
        else { Cf[idx] += v; }
      }
    }
  }
}

#define GEMM_LDS __shared__ unsigned short sA[2*64*64]; __shared__ unsigned short sW[2*128*64];

// qkv (z<12) + gate z-half (z>=12), both read z_bf, K=512
__global__ __launch_bounds__(256)
void k_qkvgate(const unsigned short* __restrict__ z_bf,
               const unsigned short* __restrict__ in_wb, const float* __restrict__ in_b,
               const unsigned short* __restrict__ gate_wb, const float* __restrict__ gate_b,
               unsigned short* __restrict__ qkv_bf, float* __restrict__ gtmp, int l,
               const int* __restrict__ action, const int* __restrict__ dof){
  GEMM_LDS
  int b = blockIdx.x; if(!dof[b]) return;
  size_t o = (size_t)(action[b]*LL + l);
  int rowbase = b*SS + blockIdx.y*64;
  int zz = blockIdx.z;
  if(zz < 12){
    mg64<0>(sA,sW, z_bf,DD, in_wb + o*3*DD*DD, DD, in_b + o*3*DD, nullptr,
            3*DD, DD, nullptr, qkv_bf, rowbase, zz*128);
  } else {
    mg64<0>(sA,sW, z_bf,DD, gate_wb + o*DD*2*DD, 2*DD, gate_b + o*DD, nullptr,
            DD, DD, gtmp, nullptr, rowbase, (zz-12)*128);
  }
}

// out-proj: ao = attno @ out_w^T + b (f32 + bf16)
__global__ __launch_bounds__(256)
void k_out(const unsigned short* __restrict__ attno_bf,
           const unsigned short* __restrict__ out_wb, const float* __restrict__ out_b,
           float* __restrict__ ao, unsigned short* __restrict__ ao_bf, int l,
           const int* __restrict__ action, const int* __restrict__ dof){
  GEMM_LDS
  int b = blockIdx.x; if(!dof[b]) return;
  size_t o = (size_t)(action[b]*LL + l);
  mg64<0>(sA,sW, attno_bf,DD, out_wb + o*DD*DD, DD, out_b + o*DD, nullptr,
          DD, DD, ao, ao_bf, b*SS + blockIdx.y*64, blockIdx.z*128);
}

// gate ao-half: gtmp += ao @ gate_w[:,512:]^T
__global__ __launch_bounds__(256)
void k_gateao(const unsigned short* __restrict__ ao_bf,
              const unsigned short* __restrict__ gate_wb,
              float* __restrict__ gtmp, int l,
              const int* __restrict__ action, const int* __restrict__ dof){
  GEMM_LDS
  int b = blockIdx.x; if(!dof[b]) return;
  size_t o = (size_t)(action[b]*LL + l);
  mg64<2>(sA,sW, ao_bf,DD, gate_wb + o*DD*2*DD + 512, 2*DD, nullptr, nullptr,
          DD, DD, gtmp, nullptr, b*SS + blockIdx.y*64, blockIdx.z*128);
}

// ffn1: ffh = gelu(z2 @ w1^T + b1)
__global__ __launch_bounds__(256)
void k_ffn1(const unsigned short* __restrict__ z2_bf,
            const unsigned short* __restrict__ f_w1b, const float* __restrict__ f_b1,
            unsigned short* __restrict__ ffh_bf, int l,
            const int* __restrict__ action, const int* __restrict__ dof){
  GEMM_LDS
  int b = blockIdx.x; if(!dof[b]) return;
  size_t o = (size_t)(action[b]*LL + l);
  mg64<1>(sA,sW, z2_bf,DD, f_w1b + o*FFF*DD, DD, f_b1 + o*FFF, nullptr,
          FFF, DD, nullptr, ffh_bf, b*SS + blockIdx.y*64, blockIdx.z*128);
}

// ffn2 split-K: half 0 -> P0 (+bias +tag at l==1), half 1 -> P1
__global__ __launch_bounds__(256)
void k_ffn2(const unsigned short* __restrict__ ffh_bf,
            const unsigned short* __restrict__ f_w2b, const float* __restrict__ f_b2,
            const float* __restrict__ tag,
            float* __restrict__ P0, float* __restrict__ P1, int l,
            const int* __restrict__ action, const int* __restrict__ dof){
  GEMM_LDS
  int b = blockIdx.x; if(!dof[b]) return;
  size_t o = (size_t)(action[b]*LL + l);
  int half = blockIdx.z >> 2, colb = (blockIdx.z & 3)*128;
  const float* bias = half ? nullptr : (f_b2 + o*DD);
  const float* tagv = (half==0 && l==LL-1) ? (tag + (size_t)action[b]*DD) : nullptr;
  mg64<0>(sA,sW, ffh_bf + half*1024, FFF, f_w2b + o*DD*FFF + half*1024, FFF,
          bias, tagv, DD, 1024, half ? P1 : P0, nullptr,
          b*SS + blockIdx.y*64, colb);
}

// ---------------- fused attention: softmax(QK^T/8) @ V, bf16 MFMA ----------------
__global__ __launch_bounds__(256)
void k_attn(const unsigned short* __restrict__ qkv, unsigned short* __restrict__ attno,
            const int* __restrict__ dof){
  int bh = blockIdx.x; int b = bh>>3, h = bh&7;
  if(!dof[b]) return;
  int q0 = blockIdx.y*64;
  __shared__ unsigned short sK[256*64];   // 32KB; reused as P after scores
  __shared__ unsigned short sVT[64*256];  // 32KB, V transposed [d][k]
  int t = threadIdx.x, l = t&63, w = t>>6;
  const unsigned short* qbase = qkv + (size_t)b*SS*1536;

  {
    int sr = t>>3, s8 = t&7;
#pragma unroll
    for(int i=0;i<8;i++){
      int r = i*32 + sr;
      int ce = ((s8<<4) ^ ((r&7)<<4)) >> 1;
      const unsigned short* gp = qbase + (size_t)r*1536 + 512 + h*64 + ce;
      __builtin_amdgcn_global_load_lds((const __attribute__((address_space(1))) void*)gp,
          (__attribute__((address_space(3))) void*)(sK + i*2048 + t*8), 16, 0, 0);
    }
  }
  {
    int kt0 = t>>2, dg = (t&3)*16;
#pragma unroll
    for(int i=0;i<4;i++){
      int kt = i*64 + kt0;
      const unsigned short* gp = qbase + (size_t)kt*1536 + 1024 + h*64 + dg;
      bf16x8 v0 = *(const bf16x8*)gp;
      bf16x8 v1 = *(const bf16x8*)(gp+8);
#pragma unroll
      for(int e=0;e<8;e++){
        int d  = dg+e;
        *(unsigned short*)((char*)sVT + d*512  + ((kt*2) ^ ((d&7)<<4)))  = (unsigned short)v0[e];
        int d2 = dg+8+e;
        *(unsigned short*)((char*)sVT + d2*512 + ((kt*2) ^ ((d2&7)<<4))) = (unsigned short)v1[e];
      }
    }
  }
  bf16x8 qf[2];
  {
    const unsigned short* qrow = qbase + (size_t)(q0 + w*16 + (l&15))*1536 + h*64;
    qf[0] = *(const bf16x8*)(qrow + ((l>>4)<<3));
    qf[1] = *(const bf16x8*)(qrow + ((l>>4)<<3) + 32);
  }
  __syncthreads();

  f32x4 sacc[16];
#pragma unroll
  for(int kb=0;kb<16;kb++) sacc[kb] = (f32x4){0.f,0.f,0.f,0.f};
#pragma unroll
  for(int kb=0;kb<16;kb++){
    int rk = kb*16 + (l&15);
#pragma unroll
    for(int ks=0;ks<2;ks++){
      bf16x8 kf = *(const bf16x8*)((const char*)sK + rk*128 + (((((l>>4)<<4)|(ks<<6))) ^ ((rk&7)<<4)));
      sacc[kb] = __builtin_amdgcn_mfma_f32_16x16x32_bf16(qf[ks], kf, sacc[kb], 0, 0, 0);
    }
  }
  float rden[4];
#pragma unroll
  for(int j=0;j<4;j++){
    float m = -1e38f;
#pragma unroll
    for(int kb=0;kb<16;kb++) m = fmaxf(m, sacc[kb][j]);
#pragma unroll
    for(int o=1;o<16;o<<=1) m = fmaxf(m, __shfl_xor(m,o,64));
    m *= 0.125f;
    float s = 0.f;
#pragma unroll
    for(int kb=0;kb<16;kb++){
      float e = expf(sacc[kb][j]*0.125f - m);
      sacc[kb][j] = e; s += e;
    }
#pragma unroll
    for(int o=1;o<16;o<<=1) s += __shfl_xor(s,o,64);
    rden[j] = 1.f/s;
  }
  __syncthreads();

  char* sP = (char*)sK + w*8192;
#pragma unroll
  for(int kb=0;kb<16;kb++){
    int k = kb*16 + (l&15);
#pragma unroll
    for(int j=0;j<4;j++){
      int qr = ((l>>4)<<2) + j;
      *(unsigned short*)(sP + qr*512 + ((k*2) ^ ((qr&7)<<4))) = bfr(sacc[kb][j]);
    }
  }
  __syncthreads();

  f32x4 oacc[4];
#pragma unroll
  for(int df=0;df<4;df++) oacc[df] = (f32x4){0.f,0.f,0.f,0.f};
#pragma unroll
  for(int kstep=0;kstep<8;kstep++){
    bf16x8 pa = *(const bf16x8*)(sP + (l&15)*512 + ((((kstep<<6)|((l>>4)<<4))) ^ ((l&7)<<4)));
#pragma unroll
    for(int df=0;df<4;df++){
      int d = df*16 + (l&15);
      bf16x8 vb = *(const bf16x8*)((char*)sVT + d*512 + ((((kstep<<6)|((l>>4)<<4))) ^ ((d&7)<<4)));
      oacc[df] = __builtin_amdgcn_mfma_f32_16x16x32_bf16(pa, vb, oacc[df], 0, 0, 0);
    }
  }
  int orow0 = b*SS + q0 + w*16 + ((l>>4)<<2);
#pragma unroll
  for(int df=0;df<4;df++){
    int col = h*64 + df*16 + (l&15);
#pragma unroll
    for(int j=0;j<4;j++)
      attno[(size_t)(orow0+j)*DD + col] = bfr(oacc[df][j]*rden[j]);
  }
}

// ---------------- gated residual + LN2 fused (x in-place) ----------------
__global__ void k_gateres_ln(const float* __restrict__ z, const float* __restrict__ ao,
                             const float* __restrict__ g, float* __restrict__ x,
                             unsigned short* __restrict__ z2b, const int* __restrict__ dof){
  int tok = blockIdx.x; if(!dof[tok>>8]) return;
  __shared__ float sh[4];
  int tid=threadIdx.x;
  size_t base=(size_t)tok*DD;
  float zz0=z[base+tid],     aa0=ao[base+tid],     gg0=g[base+tid];
  float zz1=z[base+tid+256], aa1=ao[base+tid+256], gg1=g[base+tid+256];
  float t0 = zz0 + aa0/(1.f+expf(-gg0));
  float t1 = zz1 + aa1/(1.f+expf(-gg1));
  float m = block_sum(t0+t1,sh)*(1.f/DD);
  float d0=t0-m, d1=t1-m;
  float var=block_sum(d0*d0+d1*d1,sh)*(1.f/DD);
  float inv=rsqrtf(var+1e-5f);
  float xn0 = x[base+tid]     + d0*inv;
  float xn1 = x[base+tid+256] + d1*inv;
  x[base+tid] = xn0; x[base+tid+256] = xn1;
  float m2 = block_sum(xn0+xn1,sh)*(1.f/DD);
  float e0=xn0-m2, e1=xn1-m2;
  float var2=block_sum(e0*e0+e1*e1,sh)*(1.f/DD);
  float inv2=rsqrtf(var2+1e-5f);
  z2b[base+tid] = bfr(e0*inv2); z2b[base+tid+256] = bfr(e1*inv2);
}

// ---------------- lm_head: 256x256 tile, 512 threads, 8 waves (2x4), BK=64 ----------------
__global__ __launch_bounds__(512)
void k_lmgemm(const unsigned short* __restrict__ A, const unsigned short* __restrict__ W,
              const float* __restrict__ bias, float* __restrict__ C){
  __shared__ unsigned short sA[2*256*64];  // 64KB
  __shared__ unsigned short sW[2*256*64];  // 64KB
  int t = threadIdx.x, lane = t & 63, w = t >> 6;
  int wr = w >> 2, wc = w & 3;
  int rowbase = blockIdx.y*256, colbase = blockIdx.z*256;
  int sr = t >> 3, ss8 = t & 7;

  f32x4 acc[8][4];
#pragma unroll
  for(int m=0;m<8;m++)
#pragma unroll
    for(int n=0;n<4;n++) acc[m][n] = (f32x4){0.f,0.f,0.f,0.f};

  auto STAGE = [&](int buf, int k0){
    unsigned short* dA = sA + buf*16384;
    unsigned short* dW = sW + buf*16384;
#pragma unroll
    for(int i = 0; i < 4; i++){
      int r  = i*64 + sr;
      int ce = ((ss8<<4) ^ ((r&7)<<4)) >> 1;
      const unsigned short* gp = A + (size_t)(rowbase + r)*DD + k0 + ce;
      __builtin_amdgcn_global_load_lds((const __attribute__((address_space(1))) void*)gp,
          (__attribute__((address_space(3))) void*)(dA + i*4096 + t*8), 16, 0, 0);
      const unsigned short* gw = W + (size_t)(colbase + r)*DD + k0 + ce;
      __builtin_amdgcn_global_load_lds((const __attribute__((address_space(1))) void*)gw,
          (__attribute__((address_space(3))) void*)(dW + i*4096 + t*8), 16, 0, 0);
    }
  };

  STAGE(0, 0);
  int cur = 0;
  for(int k0 = 0; k0 < DD; k0 += 64){
    if(k0 + 64 < DD){
      STAGE(cur^1, k0+64);
      asm volatile("s_waitcnt vmcnt(8)" ::: "memory");
    } else {
      asm volatile("s_waitcnt vmcnt(0)" ::: "memory");
    }
    __builtin_amdgcn_s_barrier();
    __builtin_amdgcn_sched_barrier(0);
    const char* bA = (const char*)(sA + cur*16384);
    const char* bW = (const char*)(sW + cur*16384);
#pragma unroll
    for(int ks = 0; ks < 2; ks++){
      bf16x8 af[8], wf[4];
#pragma unroll
      for(int m = 0; m < 8; m++){
        int r = wr*128 + m*16 + (lane & 15);
        af[m] = *(const bf16x8*)(bA + r*128 + (((((lane>>4)<<4)|(ks<<6))) ^ ((r&7)<<4)));
      }
#pragma unroll
      for(int n = 0; n < 4; n++){
        int r = wc*64 + n*16 + (lane & 15);
        wf[n] = *(const bf16x8*)(bW + r*128 + (((((lane>>4)<<4)|(ks<<6))) ^ ((r&7)<<4)));
      }
#pragma unroll
      for(int m = 0; m < 8; m++)
#pragma unroll
        for(int n = 0; n < 4; n++)
          acc[m][n] = __builtin_amdgcn_mfma_f32_16x16x32_bf16(af[m], wf[n], acc[m][n], 0, 0, 0);
    }
    asm volatile("s_waitcnt lgkmcnt(0)" ::: "memory");
    __builtin_amdgcn_s_barrier();
    cur ^= 1;
  }
  int orow0 = rowbase + wr*128 + ((lane >> 4) << 2);
  int ocol0 = colbase + wc*64 + (lane & 15);
#pragma unroll
  for(int m = 0; m < 8; m++){
#pragma unroll
    for(int n = 0; n < 4; n++){
      int col = ocol0 + n*16;
      float bv = bias[col];
#pragma unroll
      for(int j = 0; j < 4; j++){
        int row = orow0 + m*16 + j;
        C[(size_t)row*VV + col] = acc[m][n][j] + bv;
      }
    }
  }
}

// ---------------- host launcher ----------------
extern "C" void kernel_launch(void* const* d_in, const int* in_sizes, int n_in,
                              void* d_out, int out_size, void* d_ws, size_t ws_size,
                              hipStream_t stream){
  const int*   ids   = (const int*)d_in[0];
  const float* emb   = (const float*)d_in[1];
  const float* r_w1  = (const float*)d_in[2];
  const float* r_b1  = (const float*)d_in[3];
  const float* r_w2  = (const float*)d_in[4];
  const float* r_b2  = (const float*)d_in[5];
  const float* r_q   = (const float*)d_in[6];
  const float* in_w  = (const float*)d_in[7];
  const float* in_b  = (const float*)d_in[8];
  const float* out_w = (const float*)d_in[9];
  const float* out_b = (const float*)d_in[10];
  const float* gate_w= (const float*)d_in[11];
  const float* gate_b= (const float*)d_in[12];
  const float* f_w1  = (const float*)d_in[13];
  const float* f_b1  = (const float*)d_in[14];
  const float* f_w2  = (const float*)d_in[15];
  const float* f_b2  = (const float*)d_in[16];
  const float* tag   = (const float*)d_in[17];
  const float* lm_w  = (const float*)d_in[18];
  const float* lm_b  = (const float*)d_in[19];
  float* out = (float*)d_out;
  float* ws  = (float*)d_ws;

  const size_t M = (size_t)TOK*DD;   // 1,048,576
  float* x0     = ws;            // ping
  float* x1     = ws + 1*M;      // pong
  float* z      = ws + 2*M;
  float* ao     = ws + 3*M;
  float* gtmp   = ws + 4*M;
  float* P0     = ws + 5*M;
  float* P1     = ws + 6*M;
  float* psum   = ws + 7*M;      // 65536 f32
  int*   ipool  = (int*)(ws + 7*M + 65536);
  int* action = ipool; int* dof = ipool+BB; int* active = ipool+2*BB; int* visits = ipool+3*BB;

  unsigned short* ub = (unsigned short*)(ws + 7*M + 65536 + 64);
  unsigned short* z_bf     = ub;
  unsigned short* ao_bf    = ub + 1*M;
  unsigned short* z2_bf    = ub + 2*M;
  unsigned short* attno_bf = ub + 3*M;
  unsigned short* qkv_bf   = ub + 4*M;    // 3M
  unsigned short* ffh_bf   = ub + 7*M;    // 4M
  unsigned short* wb = ub + 11*M;
  unsigned short* in_wb   = wb;
  unsigned short* out_wb  = in_wb  + (size_t)EE*LL*3*DD*DD;
  unsigned short* gate_wb = out_wb + (size_t)EE*LL*DD*DD;
  unsigned short* f_w1b   = gate_wb+ (size_t)EE*LL*DD*2*DD;
  unsigned short* f_w2b   = f_w1b  + (size_t)EE*LL*FFF*DD;
  unsigned short* lm_wb   = f_w2b  + (size_t)EE*LL*DD*FFF;

  k_preproc<<<CASTBLK+TOK,256,0,stream>>>(in_w,out_w,gate_w,f_w1,f_w2,lm_w,
                                          in_wb,out_wb,gate_wb,f_w1b,f_w2b,lm_wb,
                                          ids, emb, x0);

  float* xc = x0;
  for(int step=0; step<3; step++){
    float* xn = (xc==x0) ? x1 : x0;
    if(step==0)
      k_lnpsum<<<TOK+128,256,0,stream>>>(xc, nullptr, nullptr, xn, z, z_bf, psum, dof);
    else{
      k_lnpsum<<<TOK+128,256,0,stream>>>(xc, P0, P1, xn, z, z_bf, psum, dof);
      xc = xn;
    }
    k_router<<<BB,256,0,stream>>>(psum,r_w1,r_b1,r_w2,r_b2,r_q,action,dof,visits,active,step);
    for(int l=0; l<LL; l++){
      if(l==1){
        float* xn2 = (xc==x0) ? x1 : x0;
        k_lnpsum<<<TOK,256,0,stream>>>(xc, P0, P1, xn2, z, z_bf, nullptr, dof);
        xc = xn2;
      }
      k_qkvgate<<<dim3(BB,4,16),256,0,stream>>>(z_bf, in_wb,in_b, gate_wb,gate_b,
                                                qkv_bf, gtmp, l, action, dof);
      k_attn<<<dim3(BB*NHH,4),256,0,stream>>>(qkv_bf, attno_bf, dof);
      k_out<<<dim3(BB,4,4),256,0,stream>>>(attno_bf, out_wb,out_b, ao, ao_bf, l, action, dof);
      k_gateao<<<dim3(BB,4,4),256,0,stream>>>(ao_bf, gate_wb, gtmp, l, action, dof);
      k_gateres_ln<<<TOK,256,0,stream>>>(z, ao, gtmp, xc, z2_bf, dof);
      k_ffn1<<<dim3(BB,4,16),256,0,stream>>>(z2_bf, f_w1b,f_b1, ffh_bf, l, action, dof);
      k_ffn2<<<dim3(BB,4,8),256,0,stream>>>(ffh_bf, f_w2b,f_b2, tag, P0, P1, l, action, dof);
    }
  }

  {
    float* xn = (xc==x0) ? x1 : x0;
    k_lnpsum<<<TOK,256,0,stream>>>(xc, P0, P1, xn, z, z_bf, nullptr, dof);
  }
  k_lmgemm<<<dim3(1,8,VV/256),512,0,stream>>>(z_bf, lm_wb, lm_b, out);
}